// Round 2
// baseline (574.804 us; speedup 1.0000x reference)
//
#include <hip/hip_runtime.h>

constexpr int B_ = 4;
constexpr int N_ = 2048;
constexpr int NFEAT_ = 256;
constexpr int NHID_ = 64;
constexpr int NHEADS_ = 8;
constexpr int NOUT_ = 128;
constexpr float SLOPE_ = 0.1f;
constexpr float NEGV = -9000000000000000.0f;

// ---------------------------------------------------------------------------
// GEMM1: h1[b][n][head*64+f] = sum_k x[b][n][k] * Wh[head][k][f]   (f32)
// fused: s1h/s2h[(b*8+head)*N + n] = h . a1 / h . a2
// block = (b, 8-row n-tile), 256 threads = (head 8) x (fpair 32)
// ---------------------------------------------------------------------------
__global__ __launch_bounds__(256) void k_gemm1(
    const float* __restrict__ x, const float* __restrict__ Wh,
    const float* __restrict__ ah,
    float* __restrict__ h1, float* __restrict__ s1h, float* __restrict__ s2h)
{
  int t = threadIdx.x;
  int bid = blockIdx.x;
  int b = bid / (N_ / 8);
  int n0 = (bid % (N_ / 8)) * 8;

  __shared__ float sx[8][NFEAT_];
  #pragma unroll
  for (int k = 0; k < 2; ++k) {             // 8*256 floats = 512 float4
    int idx4 = t + k * 256;
    int r = idx4 >> 6, c4 = idx4 & 63;
    *(float4*)&sx[r][c4 * 4] =
        *(const float4*)&x[(size_t)(b * N_ + n0 + r) * NFEAT_ + c4 * 4];
  }
  __syncthreads();

  int head = t >> 5, fp = t & 31;           // f = 2*fp, 2*fp+1
  float acc0[8], acc1[8];
  #pragma unroll
  for (int r = 0; r < 8; ++r) { acc0[r] = 0.f; acc1[r] = 0.f; }

  const float* wbase = Wh + (size_t)head * NFEAT_ * NHID_ + 2 * fp;
  for (int k = 0; k < NFEAT_; ++k) {
    float2 w = *(const float2*)(wbase + (size_t)k * NHID_);
    #pragma unroll
    for (int r = 0; r < 8; ++r) {
      float xv = sx[r][k];
      acc0[r] = fmaf(xv, w.x, acc0[r]);
      acc1[r] = fmaf(xv, w.y, acc1[r]);
    }
  }

  #pragma unroll
  for (int r = 0; r < 8; ++r) {
    float2 v = make_float2(acc0[r], acc1[r]);
    *(float2*)&h1[(size_t)(b * N_ + n0 + r) * 512 + head * 64 + 2 * fp] = v;
  }

  // s-dots: reduce over the 32 fp-lanes of this head (xor<32 stays in group)
  float a1_0 = ah[head * 128 + 2 * fp];
  float a1_1 = ah[head * 128 + 2 * fp + 1];
  float a2_0 = ah[head * 128 + 64 + 2 * fp];
  float a2_1 = ah[head * 128 + 64 + 2 * fp + 1];
  #pragma unroll
  for (int r = 0; r < 8; ++r) {
    float v1 = acc0[r] * a1_0 + acc1[r] * a1_1;
    float v2 = acc0[r] * a2_0 + acc1[r] * a2_1;
    #pragma unroll
    for (int off = 1; off < 32; off <<= 1) {
      v1 += __shfl_xor(v1, off, 64);
      v2 += __shfl_xor(v2, off, 64);
    }
    if (fp == 0) {
      s1h[(size_t)(b * NHEADS_ + head) * N_ + n0 + r] = v1;
      s2h[(size_t)(b * NHEADS_ + head) * N_ + n0 + r] = v2;
    }
  }
}

// ---------------------------------------------------------------------------
// GEMM2: h2[b][n][f] = sum_k g1[b][n][k] * Wo[k][f]  (k=512, f=128)
// fused s1o/s2o[b*N+n] = h2 . ao[:128] / h2 . ao[128:]
// block = (b, 8-row n-tile), 128 threads = one f each
// ---------------------------------------------------------------------------
__global__ __launch_bounds__(128) void k_gemm2(
    const float* __restrict__ g1, const float* __restrict__ Wo,
    const float* __restrict__ ao,
    float* __restrict__ h2, float* __restrict__ s1o, float* __restrict__ s2o)
{
  int t = threadIdx.x;
  int bid = blockIdx.x;
  int b = bid / (N_ / 8);
  int n0 = (bid % (N_ / 8)) * 8;

  __shared__ float sg[8][512];
  #pragma unroll
  for (int k = 0; k < 8; ++k) {
    int idx4 = t + k * 128;                 // 1024 float4s
    int r = idx4 >> 7, c4 = idx4 & 127;
    *(float4*)&sg[r][c4 * 4] =
        *(const float4*)&g1[(size_t)(b * N_ + n0 + r) * 512 + c4 * 4];
  }
  __syncthreads();

  float acc[8];
  #pragma unroll
  for (int r = 0; r < 8; ++r) acc[r] = 0.f;
  for (int k = 0; k < 512; ++k) {
    float w = Wo[(size_t)k * 128 + t];
    #pragma unroll
    for (int r = 0; r < 8; ++r) acc[r] = fmaf(sg[r][k], w, acc[r]);
  }
  #pragma unroll
  for (int r = 0; r < 8; ++r)
    h2[(size_t)(b * N_ + n0 + r) * 128 + t] = acc[r];

  float aov1 = ao[t];
  float aov2 = ao[128 + t];
  __shared__ float ps1[2][8], ps2[2][8];
  int wv = t >> 6, lane = t & 63;
  #pragma unroll
  for (int r = 0; r < 8; ++r) {
    float v1 = acc[r] * aov1, v2 = acc[r] * aov2;
    #pragma unroll
    for (int off = 1; off < 64; off <<= 1) {
      v1 += __shfl_xor(v1, off, 64);
      v2 += __shfl_xor(v2, off, 64);
    }
    if (lane == 0) { ps1[wv][r] = v1; ps2[wv][r] = v2; }
  }
  __syncthreads();
  if (t < 8)       s1o[(size_t)b * N_ + n0 + t] = ps1[0][t] + ps1[1][t];
  else if (t < 16) { int r = t - 8; s2o[(size_t)b * N_ + n0 + r] = ps2[0][r] + ps2[1][r]; }
}

// ---------------------------------------------------------------------------
// Fused GAT attention, flash-style online softmax.
//   e[i][j] = adj>0 ? leaky(s1[i]+s2[j]) : NEG ;  att = softmax_j ;
//   out[i][f] = epilogue( (sum_j w*h[j][f]) / L + bias[f] )
// block = (b, head, TI-row tile), 256 threads.
// Per TJ=64 tile: e once per (i,j) into regs; cooperative row-max; w staged
// transposed wT[j][i] so FMA phase does float4 reads of w and h (4x4 tiles).
// EPI==0: elu -> f32 gout (layer-1 concat layout). EPI==1: relu -> f32 out.
// ---------------------------------------------------------------------------
template<int TI, int FDIM, int H, int S, int EPI>
__global__ __launch_bounds__(256) void k_att(
    const float* __restrict__ hsrc, const float* __restrict__ s1,
    const float* __restrict__ s2, const int* __restrict__ adj,
    const float* __restrict__ bias,
    float* __restrict__ gout)
{
  constexpr int TJ = 64;
  constexpr int RI = 4, FW = 4;
  constexpr int NFG = FDIM / FW;            // f-groups
  constexpr int NIG = TI / RI;              // row-groups
  static_assert(NFG * NIG == 256, "block mapping");
  constexpr int TPR = 256 / TI;             // threads per row (e phase)
  constexpr int EC  = TJ / TPR;             // e elems per thread
  constexpr int NT  = N_ / TI;

  int t = threadIdx.x;
  int bid = blockIdx.x;
  int it = bid % NT;
  int head = (bid / NT) % H;
  int b = bid / (NT * H);
  int i0 = it * TI;

  __shared__ float wT[TJ][TI];              // transposed attention weights
  __shared__ float hT[TJ][FDIM];
  __shared__ float s2row[N_];
  __shared__ float s1T[TI], Mrow[TI], Lrow[TI], scT[TI];
  __shared__ float pmax[TI][TPR], psum[TI][TPR];

  const float* s1p = s1 + (size_t)(b * H + head) * N_;
  const float* s2p = s2 + (size_t)(b * H + head) * N_;

  if (t < TI) { s1T[t] = s1p[i0 + t]; Mrow[t] = -INFINITY; Lrow[t] = 0.f; }
  #pragma unroll
  for (int k = 0; k < N_ / 256; ++k) s2row[t + k * 256] = s2p[t + k * 256];

  int ig = t / NFG, fg = t % NFG;
  float acc[RI][FW];
  #pragma unroll
  for (int r = 0; r < RI; ++r)
    #pragma unroll
    for (int c = 0; c < FW; ++c) acc[r][c] = 0.f;

  int iie = t / TPR, jc = t % TPR;
  const int* adjrow = adj + ((size_t)b * N_ + (i0 + iie)) * N_ + jc * EC;

  for (int j0 = 0; j0 < N_; j0 += TJ) {
    __syncthreads();                                    // protect wT/hT/pmax reuse
    // stage h tile
    constexpr int NL4 = TJ * FDIM / 4 / 256;
    #pragma unroll
    for (int k = 0; k < NL4; ++k) {
      int idx = t + k * 256;
      int jj = idx / (FDIM / 4), c4 = idx % (FDIM / 4);
      *(float4*)&hT[jj][c4 * 4] =
          *(const float4*)&hsrc[(size_t)(b * N_ + j0 + jj) * S + head * FDIM + c4 * 4];
    }
    // e phase (registers only)
    float ev[EC];
    float pmx = -INFINITY;
    {
      float s1v = s1T[iie];
      const int* arow = adjrow + j0;
      #pragma unroll
      for (int q4 = 0; q4 < EC / 4; ++q4) {
        int4 a4 = *(const int4*)(arow + q4 * 4);
        int aa[4] = {a4.x, a4.y, a4.z, a4.w};
        #pragma unroll
        for (int e = 0; e < 4; ++e) {
          int q = q4 * 4 + e;
          float v = s1v + s2row[j0 + jc * EC + q];
          v = (v >= 0.f) ? v : SLOPE_ * v;
          float evv = (aa[e] > 0) ? v : NEGV;
          ev[q] = evv;
          pmx = fmaxf(pmx, evv);
        }
      }
    }
    pmax[iie][jc] = pmx;
    __syncthreads();
    // P1: per-row new max + rescale factor
    if (t < TI) {
      float mx = pmax[t][0];
      #pragma unroll
      for (int c = 1; c < TPR; ++c) mx = fmaxf(mx, pmax[t][c]);
      float mold = Mrow[t];
      float mnew = fmaxf(mold, mx);
      scT[t] = __expf(mold - mnew);          // exp(-inf)=0 on first tile
      Mrow[t] = mnew;
    }
    __syncthreads();
    // P2: exponentiate, stage wT (transposed), partial row sums
    {
      float mrow = Mrow[iie];
      float ps = 0.f;
      #pragma unroll
      for (int q = 0; q < EC; ++q) {
        float w = __expf(ev[q] - mrow);
        wT[jc * EC + q][iie] = w;
        ps += w;
      }
      psum[iie][jc] = ps;
    }
    __syncthreads();
    // P2b: L update (concurrent with P3; disjoint shared data, both read scT)
    if (t < TI) {
      float ssum = 0.f;
      #pragma unroll
      for (int c = 0; c < TPR; ++c) ssum += psum[t][c];
      Lrow[t] = Lrow[t] * scT[t] + ssum;
    }
    // P3: rescale accumulators, then 4x4 register-tiled FMA over tile
    float scr[RI];
    #pragma unroll
    for (int r = 0; r < RI; ++r) scr[r] = scT[ig * RI + r];
    #pragma unroll
    for (int r = 0; r < RI; ++r)
      #pragma unroll
      for (int c = 0; c < FW; ++c) acc[r][c] *= scr[r];
    #pragma unroll 4
    for (int jj = 0; jj < TJ; ++jj) {
      float4 h4 = *(float4*)&hT[jj][fg * FW];
      float4 w4 = *(float4*)&wT[jj][ig * RI];
      acc[0][0] = fmaf(w4.x, h4.x, acc[0][0]);
      acc[0][1] = fmaf(w4.x, h4.y, acc[0][1]);
      acc[0][2] = fmaf(w4.x, h4.z, acc[0][2]);
      acc[0][3] = fmaf(w4.x, h4.w, acc[0][3]);
      acc[1][0] = fmaf(w4.y, h4.x, acc[1][0]);
      acc[1][1] = fmaf(w4.y, h4.y, acc[1][1]);
      acc[1][2] = fmaf(w4.y, h4.z, acc[1][2]);
      acc[1][3] = fmaf(w4.y, h4.w, acc[1][3]);
      acc[2][0] = fmaf(w4.z, h4.x, acc[2][0]);
      acc[2][1] = fmaf(w4.z, h4.y, acc[2][1]);
      acc[2][2] = fmaf(w4.z, h4.z, acc[2][2]);
      acc[2][3] = fmaf(w4.z, h4.w, acc[2][3]);
      acc[3][0] = fmaf(w4.w, h4.x, acc[3][0]);
      acc[3][1] = fmaf(w4.w, h4.y, acc[3][1]);
      acc[3][2] = fmaf(w4.w, h4.z, acc[3][2]);
      acc[3][3] = fmaf(w4.w, h4.w, acc[3][3]);
    }
  }
  __syncthreads();                           // Lrow final
  // epilogue
  #pragma unroll
  for (int r = 0; r < RI; ++r) {
    int row = ig * RI + r;
    int i = i0 + row;
    float inv = 1.0f / Lrow[row];
    float4 vout;
    float* vp = &vout.x;
    #pragma unroll
    for (int c = 0; c < FW; ++c) {
      int f = fg * FW + c;
      float v = acc[r][c] * inv + bias[head * FDIM + f];
      if constexpr (EPI == 0)
        vp[c] = (v > 0.f) ? v : expm1f(v);   // elu
      else
        vp[c] = fmaxf(v, 0.f);               // relu(elu(x)) == relu(x)
    }
    if constexpr (EPI == 0)
      *(float4*)&gout[(size_t)(b * N_ + i) * S + head * FDIM + fg * FW] = vout;
    else
      *(float4*)&gout[(size_t)(b * N_ + i) * FDIM + fg * FW] = vout;
  }
}

// ---------------------------------------------------------------------------
extern "C" void kernel_launch(void* const* d_in, const int* in_sizes, int n_in,
                              void* d_out, int out_size, void* d_ws, size_t ws_size,
                              hipStream_t stream) {
  const float* x   = (const float*)d_in[0];
  const int*   adj = (const int*)d_in[1];
  const float* Wh  = (const float*)d_in[2];
  const float* ah  = (const float*)d_in[3];
  const float* bh  = (const float*)d_in[4];
  const float* Wo  = (const float*)d_in[5];
  const float* ao  = (const float*)d_in[6];
  const float* bo  = (const float*)d_in[7];
  float* out = (float*)d_out;

  float* ws  = (float*)d_ws;
  float* h1  = ws;                                    // B*N*512
  float* s1h = h1  + (size_t)B_ * N_ * 512;           // B*8*N
  float* s2h = s1h + (size_t)B_ * NHEADS_ * N_;       // B*8*N
  float* g1  = s2h + (size_t)B_ * NHEADS_ * N_;       // B*N*512
  float* h2  = g1  + (size_t)B_ * N_ * 512;           // B*N*128
  float* s1o = h2  + (size_t)B_ * N_ * 128;           // B*N
  float* s2o = s1o + (size_t)B_ * N_;                 // B*N

  k_gemm1<<<B_ * N_ / 8, 256, 0, stream>>>(x, Wh, ah, h1, s1h, s2h);
  k_att<64, 64, NHEADS_, 512, 0><<<B_ * NHEADS_ * (N_ / 64), 256, 0, stream>>>(
      h1, s1h, s2h, adj, bh, g1);
  k_gemm2<<<B_ * N_ / 8, 128, 0, stream>>>(g1, Wo, ao, h2, s1o, s2o);
  k_att<32, 128, 1, 128, 1><<<B_ * (N_ / 32), 256, 0, stream>>>(
      h2, s1o, s2o, adj, bo, out);
}

// Round 3
// 301.411 us; speedup vs baseline: 1.9070x; 1.9070x over previous
//
#include <hip/hip_runtime.h>

constexpr int B_ = 4;
constexpr int N_ = 2048;
constexpr int NFEAT_ = 256;
constexpr int NHEADS_ = 8;
constexpr float SLOPE_ = 0.1f;

typedef __attribute__((ext_vector_type(8))) short bf16x8;
typedef __attribute__((ext_vector_type(4))) float f32x4;

__device__ __forceinline__ unsigned short f2bf(float f) {
  union { float f; unsigned int u; } v; v.f = f;
  return (unsigned short)((v.u + 0x8000u) >> 16);   // round-half-up to bf16
}

// ---------------------------------------------------------------------------
// adj (int32 0/1) -> bitmask, bit (i*N+j)%8 of byte (i*N+j)/8, LSB-first.
// One thread per 32 ints -> one u32 store. 64 MB read, 2 MB write.
// ---------------------------------------------------------------------------
__global__ __launch_bounds__(256) void k_packadj(
    const int* __restrict__ adj, unsigned int* __restrict__ bits)
{
  size_t tid = (size_t)blockIdx.x * 256 + threadIdx.x;
  const int* p = adj + tid * 32;
  unsigned int m = 0;
  #pragma unroll
  for (int q = 0; q < 8; ++q) {
    int4 a = *(const int4*)(p + q * 4);
    m |= (a.x > 0 ? 1u : 0u) << (q * 4 + 0);
    m |= (a.y > 0 ? 1u : 0u) << (q * 4 + 1);
    m |= (a.z > 0 ? 1u : 0u) << (q * 4 + 2);
    m |= (a.w > 0 ? 1u : 0u) << (q * 4 + 3);
  }
  bits[tid] = m;
}

// ---------------------------------------------------------------------------
// GEMM1: h[b][n][head*64+f] = sum_k x[b][n][k] * Wh[head][k][f]
// Output: hB1 bf16 in MFMA B-fragment order [b*8+head][kstep][ftile][lane][8]
//   (lane slot = ((n0>>3)&3)*16 + (f&15); elems = 8 consecutive n)
// fused: s1h/s2h = h.a1 / h.a2
// block = (b, 8-row n-tile), 256 threads = (head 8) x (fpair 32)
// ---------------------------------------------------------------------------
__global__ __launch_bounds__(256) void k_gemm1(
    const float* __restrict__ x, const float* __restrict__ Wh,
    const float* __restrict__ ah,
    unsigned short* __restrict__ hB1, float* __restrict__ s1h, float* __restrict__ s2h)
{
  int t = threadIdx.x;
  int bid = blockIdx.x;
  int b = bid / (N_ / 8);
  int n0 = (bid % (N_ / 8)) * 8;

  __shared__ float sx[8][NFEAT_];
  #pragma unroll
  for (int k = 0; k < 2; ++k) {
    int idx4 = t + k * 256;
    int r = idx4 >> 6, c4 = idx4 & 63;
    *(float4*)&sx[r][c4 * 4] =
        *(const float4*)&x[(size_t)(b * N_ + n0 + r) * NFEAT_ + c4 * 4];
  }
  __syncthreads();

  int head = t >> 5, fp = t & 31;           // f = 2*fp, 2*fp+1
  float acc0[8], acc1[8];
  #pragma unroll
  for (int r = 0; r < 8; ++r) { acc0[r] = 0.f; acc1[r] = 0.f; }

  const float* wbase = Wh + (size_t)head * NFEAT_ * 64 + 2 * fp;
  for (int k = 0; k < NFEAT_; ++k) {
    float2 w = *(const float2*)(wbase + (size_t)k * 64);
    #pragma unroll
    for (int r = 0; r < 8; ++r) {
      float xv = sx[r][k];
      acc0[r] = fmaf(xv, w.x, acc0[r]);
      acc1[r] = fmaf(xv, w.y, acc1[r]);
    }
  }

  // pack into hB1 fragment order (this block's 8 rows = one elem-octet)
  {
    int ftile = fp >> 3;                    // (2fp)>>4
    int lane0 = ((n0 >> 3) & 3) * 16 + ((2 * fp) & 15);
    unsigned short* dst = hB1 +
        ((((size_t)(b * NHEADS_ + head) * 64 + (n0 >> 5)) * 4 + ftile) * 512 + (size_t)lane0 * 8);
    union { short s[8]; bf16x8 v; } p0, p1;
    #pragma unroll
    for (int r = 0; r < 8; ++r) { p0.s[r] = (short)f2bf(acc0[r]); p1.s[r] = (short)f2bf(acc1[r]); }
    *(bf16x8*)dst = p0.v;
    *(bf16x8*)(dst + 8) = p1.v;
  }

  // fused s-dots (reduce across 32 fp-lanes of this head)
  float a1_0 = ah[head * 128 + 2 * fp];
  float a1_1 = ah[head * 128 + 2 * fp + 1];
  float a2_0 = ah[head * 128 + 64 + 2 * fp];
  float a2_1 = ah[head * 128 + 64 + 2 * fp + 1];
  #pragma unroll
  for (int r = 0; r < 8; ++r) {
    float v1 = acc0[r] * a1_0 + acc1[r] * a1_1;
    float v2 = acc0[r] * a2_0 + acc1[r] * a2_1;
    #pragma unroll
    for (int off = 1; off < 32; off <<= 1) {
      v1 += __shfl_xor(v1, off, 64);
      v2 += __shfl_xor(v2, off, 64);
    }
    if (fp == 0) {
      s1h[(size_t)(b * NHEADS_ + head) * N_ + n0 + r] = v1;
      s2h[(size_t)(b * NHEADS_ + head) * N_ + n0 + r] = v2;
    }
  }
}

// ---------------------------------------------------------------------------
// GEMM2: h2[b][n][f] = sum_k g1[b][n][k] * Wo[k][f]  (k=512, f=128)
// Output: hB2 bf16 B-fragment order [b][kstep][ftile 8][lane][8]
// fused s1o/s2o.  block = (b, 8-row n-tile), 128 threads = one f each
// ---------------------------------------------------------------------------
__global__ __launch_bounds__(128) void k_gemm2(
    const float* __restrict__ g1, const float* __restrict__ Wo,
    const float* __restrict__ ao,
    unsigned short* __restrict__ hB2, float* __restrict__ s1o, float* __restrict__ s2o)
{
  int t = threadIdx.x;
  int bid = blockIdx.x;
  int b = bid / (N_ / 8);
  int n0 = (bid % (N_ / 8)) * 8;

  __shared__ float sg[8][512];
  #pragma unroll
  for (int k = 0; k < 8; ++k) {
    int idx4 = t + k * 128;
    int r = idx4 >> 7, c4 = idx4 & 127;
    *(float4*)&sg[r][c4 * 4] =
        *(const float4*)&g1[(size_t)(b * N_ + n0 + r) * 512 + c4 * 4];
  }
  __syncthreads();

  float acc[8];
  #pragma unroll
  for (int r = 0; r < 8; ++r) acc[r] = 0.f;
  for (int k = 0; k < 512; ++k) {
    float w = Wo[(size_t)k * 128 + t];
    #pragma unroll
    for (int r = 0; r < 8; ++r) acc[r] = fmaf(sg[r][k], w, acc[r]);
  }

  // pack into hB2 fragment order
  {
    int ftile = t >> 4;
    int lane0 = ((n0 >> 3) & 3) * 16 + (t & 15);
    unsigned short* dst = hB2 +
        ((((size_t)b * 64 + (n0 >> 5)) * 8 + ftile) * 512 + (size_t)lane0 * 8);
    union { short s[8]; bf16x8 v; } p0;
    #pragma unroll
    for (int r = 0; r < 8; ++r) p0.s[r] = (short)f2bf(acc[r]);
    *(bf16x8*)dst = p0.v;
  }

  float aov1 = ao[t];
  float aov2 = ao[128 + t];
  __shared__ float ps1[2][8], ps2[2][8];
  int wv = t >> 6, lane = t & 63;
  #pragma unroll
  for (int r = 0; r < 8; ++r) {
    float v1 = acc[r] * aov1, v2 = acc[r] * aov2;
    #pragma unroll
    for (int off = 1; off < 64; off <<= 1) {
      v1 += __shfl_xor(v1, off, 64);
      v2 += __shfl_xor(v2, off, 64);
    }
    if (lane == 0) { ps1[wv][r] = v1; ps2[wv][r] = v2; }
  }
  __syncthreads();
  if (t < 8)       s1o[(size_t)b * N_ + n0 + t] = ps1[0][t] + ps1[1][t];
  else if (t < 16) { int r = t - 8; s2o[(size_t)b * N_ + n0 + r] = ps2[0][r] + ps2[1][r]; }
}

// ---------------------------------------------------------------------------
// MFMA flash attention. One wave owns 16 i-rows x 64 f; no LDS, no syncthreads.
// e built in A-fragment order in registers (lane: row=l&15, j=quad*8+{0..7});
// V read from pre-packed bf16 B-fragments (linear 16B/lane global loads);
// adj from bitmask. Online softmax with unmasked max (valid: mask after exp).
// EPI0: elu -> g1 f32 (layer-1, H=8, FDIM=64). EPI1: relu -> out (f-split x2).
// ---------------------------------------------------------------------------
template<int EPI>
__global__ __launch_bounds__(256) void k_att_mfma(
    const unsigned short* __restrict__ hB, const float* __restrict__ s1,
    const float* __restrict__ s2, const unsigned char* __restrict__ adjb,
    const float* __restrict__ bias, float* __restrict__ outp)
{
  constexpr int H    = (EPI == 0) ? 8 : 1;
  constexpr int NFT  = (EPI == 0) ? 4 : 8;    // ftiles stored per kstep
  constexpr int KSTR = NFT * 512;             // bf16 elems per kstep
  constexpr int OSTR = (EPI == 0) ? 512 : 128;

  const int tid = threadIdx.x;
  const int l = tid & 63, wv = tid >> 6;
  const int quad = l >> 4, c15 = l & 15;

  const int bid = blockIdx.x;
  const int ig = bid & 31;                    // N/64 row-groups
  int head, b, fs;
  if constexpr (EPI == 0) { head = (bid >> 5) & 7; b = bid >> 8; fs = 0; }
  else                    { head = 0; fs = (bid >> 5) & 1; b = bid >> 6; }

  const int i0w = ig * 64 + wv * 16;
  const int colbase = (EPI == 0) ? head * 64 : fs * 64;

  const float* s1p = s1 + (size_t)(b * H + head) * N_;
  const float* s2p = s2 + (size_t)(b * H + head) * N_;
  const unsigned short* hBp = hB + (size_t)(b * H + head) * (N_ / 32) * KSTR + fs * 2048;
  const unsigned char* abp = adjb + ((size_t)(b * N_) + i0w + c15) * (N_ / 8);

  const float s1v = s1p[i0w + c15];
  float m = -INFINITY, ldn = 0.f;
  f32x4 acc[4];
  #pragma unroll
  for (int t = 0; t < 4; ++t) acc[t] = (f32x4){0.f, 0.f, 0.f, 0.f};

  for (int j0 = 0; j0 < N_; j0 += 64) {
    // B-fragments: linear per-wave 16B loads (prefetched, hidden behind e-phase)
    const unsigned short* hk0 = hBp + (size_t)(j0 >> 5) * KSTR + (size_t)l * 8;
    const unsigned short* hk1 = hk0 + KSTR;
    bf16x8 bf0[4], bf1[4];
    #pragma unroll
    for (int t = 0; t < 4; ++t) {
      bf0[t] = *(const bf16x8*)(hk0 + t * 512);
      bf1[t] = *(const bf16x8*)(hk1 + t * 512);
    }
    const unsigned int mb0 = abp[(j0 >> 3) + quad];
    const unsigned int mb1 = abp[(j0 >> 3) + 4 + quad];
    float s2r[16];
    *(float4*)&s2r[0]  = *(const float4*)(s2p + j0 + quad * 8);
    *(float4*)&s2r[4]  = *(const float4*)(s2p + j0 + quad * 8 + 4);
    *(float4*)&s2r[8]  = *(const float4*)(s2p + j0 + 32 + quad * 8);
    *(float4*)&s2r[12] = *(const float4*)(s2p + j0 + 32 + quad * 8 + 4);

    // e = leaky(s1+s2) (unmasked); row-max across 16 local + 4 quads
    float ev[16], tmax = -INFINITY;
    #pragma unroll
    for (int k = 0; k < 16; ++k) {
      float v = s1v + s2r[k];
      v = fmaxf(v, SLOPE_ * v);               // leaky, slope<1
      ev[k] = v;
      tmax = fmaxf(tmax, v);
    }
    tmax = fmaxf(tmax, __shfl_xor(tmax, 16));
    tmax = fmaxf(tmax, __shfl_xor(tmax, 32));
    const float mnew = fmaxf(m, tmax);
    const float scf = __expf(m - mnew);       // exp(-inf)=0 first tile
    m = mnew;

    // w = exp(e-m) * maskbit; row-sum
    float w[16], ls = 0.f;
    #pragma unroll
    for (int k = 0; k < 8; ++k) {
      float e = __expf(ev[k] - mnew);
      e = ((mb0 >> k) & 1u) ? e : 0.f;
      w[k] = e; ls += e;
    }
    #pragma unroll
    for (int k = 0; k < 8; ++k) {
      float e = __expf(ev[8 + k] - mnew);
      e = ((mb1 >> k) & 1u) ? e : 0.f;
      w[8 + k] = e; ls += e;
    }
    ls += __shfl_xor(ls, 16);
    ls += __shfl_xor(ls, 32);
    ldn = ldn * scf + ls;

    // A-fragments (already in fragment order by construction)
    union { short s[8]; bf16x8 v; } a0, a1;
    #pragma unroll
    for (int k = 0; k < 8; ++k) {
      a0.s[k] = (short)f2bf(w[k]);
      a1.s[k] = (short)f2bf(w[8 + k]);
    }

    // rescale acc rows (C rows = quad*4+r; fetch sc from A-layout holder lane)
    f32x4 scv;
    scv.x = __shfl(scf, quad * 4 + 0);
    scv.y = __shfl(scf, quad * 4 + 1);
    scv.z = __shfl(scf, quad * 4 + 2);
    scv.w = __shfl(scf, quad * 4 + 3);
    #pragma unroll
    for (int t = 0; t < 4; ++t) acc[t] *= scv;

    #pragma unroll
    for (int t = 0; t < 4; ++t) {
      acc[t] = __builtin_amdgcn_mfma_f32_16x16x32_bf16(a0.v, bf0[t], acc[t], 0, 0, 0);
      acc[t] = __builtin_amdgcn_mfma_f32_16x16x32_bf16(a1.v, bf1[t], acc[t], 0, 0, 0);
    }
  }

  // epilogue: /L, +bias, activation, store (C layout: col=c15, row=quad*4+r)
  float lr[4];
  lr[0] = 1.f / __shfl(ldn, quad * 4 + 0);
  lr[1] = 1.f / __shfl(ldn, quad * 4 + 1);
  lr[2] = 1.f / __shfl(ldn, quad * 4 + 2);
  lr[3] = 1.f / __shfl(ldn, quad * 4 + 3);
  #pragma unroll
  for (int t = 0; t < 4; ++t) {
    const float bv = bias[colbase + t * 16 + c15];
    #pragma unroll
    for (int r = 0; r < 4; ++r) {
      const int i = i0w + quad * 4 + r;
      float v = acc[t][r] * lr[r] + bv;
      if constexpr (EPI == 0) v = (v > 0.f) ? v : expm1f(v);  // elu
      else                    v = fmaxf(v, 0.f);              // relu(elu)=relu
      outp[(size_t)(b * N_ + i) * OSTR + colbase + t * 16 + c15] = v;
    }
  }
}

// ---------------------------------------------------------------------------
extern "C" void kernel_launch(void* const* d_in, const int* in_sizes, int n_in,
                              void* d_out, int out_size, void* d_ws, size_t ws_size,
                              hipStream_t stream) {
  const float* x   = (const float*)d_in[0];
  const int*   adj = (const int*)d_in[1];
  const float* Wh  = (const float*)d_in[2];
  const float* ah  = (const float*)d_in[3];
  const float* bh  = (const float*)d_in[4];
  const float* Wo  = (const float*)d_in[5];
  const float* ao  = (const float*)d_in[6];
  const float* bo  = (const float*)d_in[7];
  float* out = (float*)d_out;

  float* g1  = (float*)d_ws;                          // B*N*512 f32 (16 MB)
  float* s1h = g1  + (size_t)B_ * N_ * 512;           // B*8*N
  float* s2h = s1h + (size_t)B_ * NHEADS_ * N_;
  float* s1o = s2h + (size_t)B_ * NHEADS_ * N_;       // B*N
  float* s2o = s1o + (size_t)B_ * N_;
  unsigned short* hB1 = (unsigned short*)(s2o + (size_t)B_ * N_);   // 8 MB
  unsigned short* hB2 = hB1 + (size_t)B_ * NHEADS_ * N_ * 64;       // 2 MB
  unsigned int*  abit = (unsigned int*)(hB2 + (size_t)B_ * N_ * 128); // 2 MB

  k_packadj<<<(B_ * N_ * N_ / 32) / 256, 256, 0, stream>>>(adj, abit);
  k_gemm1<<<B_ * N_ / 8, 256, 0, stream>>>(x, Wh, ah, hB1, s1h, s2h);
  k_att_mfma<0><<<B_ * NHEADS_ * (N_ / 64), 256, 0, stream>>>(
      hB1, s1h, s2h, (const unsigned char*)abit, bh, g1);
  k_gemm2<<<B_ * N_ / 8, 128, 0, stream>>>(g1, Wo, ao, hB2, s1o, s2o);
  k_att_mfma<1><<<B_ * 2 * (N_ / 64), 256, 0, stream>>>(
      hB2, s1o, s2o, (const unsigned char*)abit, bo, out);
}

// Round 5
// 287.861 us; speedup vs baseline: 1.9968x; 1.0471x over previous
//
#include <hip/hip_runtime.h>

constexpr int B_ = 4;
constexpr int N_ = 2048;
constexpr int NFEAT_ = 256;
constexpr int NHEADS_ = 8;
constexpr float SLOPE_ = 0.1f;
constexpr float L2E = 1.4426950408889634f;   // log2(e)

typedef __attribute__((ext_vector_type(8))) __fp16 f16x8;
typedef __attribute__((ext_vector_type(2))) __fp16 f16x2;
typedef __attribute__((ext_vector_type(4))) float f32x4;

__device__ __forceinline__ f16x8 pack8(const float* v) {
  union { f16x2 h2[4]; f16x8 h8; } u;
  u.h2[0] = __builtin_amdgcn_cvt_pkrtz(v[0], v[1]);
  u.h2[1] = __builtin_amdgcn_cvt_pkrtz(v[2], v[3]);
  u.h2[2] = __builtin_amdgcn_cvt_pkrtz(v[4], v[5]);
  u.h2[3] = __builtin_amdgcn_cvt_pkrtz(v[6], v[7]);
  return u.h8;
}

// ---------------------------------------------------------------------------
// adj (int32 0/1) -> bitmask, LSB-first. One thread per 32 ints.
// ---------------------------------------------------------------------------
__global__ __launch_bounds__(256) void k_packadj(
    const int* __restrict__ adj, unsigned int* __restrict__ bits)
{
  size_t tid = (size_t)blockIdx.x * 256 + threadIdx.x;
  const int* p = adj + tid * 32;
  unsigned int m = 0;
  #pragma unroll
  for (int q = 0; q < 8; ++q) {
    int4 a = *(const int4*)(p + q * 4);
    m |= (a.x > 0 ? 1u : 0u) << (q * 4 + 0);
    m |= (a.y > 0 ? 1u : 0u) << (q * 4 + 1);
    m |= (a.z > 0 ? 1u : 0u) << (q * 4 + 2);
    m |= (a.w > 0 ? 1u : 0u) << (q * 4 + 3);
  }
  bits[tid] = m;
}

// ---------------------------------------------------------------------------
// row max over N_ (for s2max): exact unmasked attention row-max precompute.
// ---------------------------------------------------------------------------
__global__ __launch_bounds__(256) void k_rowmax(
    const float* __restrict__ src, float* __restrict__ dst)
{
  int row = blockIdx.x, t = threadIdx.x;
  const float* p = src + (size_t)row * N_;
  float m = -INFINITY;
  #pragma unroll
  for (int k = 0; k < N_ / 256; ++k) m = fmaxf(m, p[t + k * 256]);
  #pragma unroll
  for (int off = 1; off < 64; off <<= 1) m = fmaxf(m, __shfl_xor(m, off, 64));
  __shared__ float sm[4];
  if ((t & 63) == 0) sm[t >> 6] = m;
  __syncthreads();
  if (t == 0) dst[row] = fmaxf(fmaxf(sm[0], sm[1]), fmaxf(sm[2], sm[3]));
}

// ---------------------------------------------------------------------------
// GEMM1: h = x@Wh per head; hB1 = f16 MFMA-B-fragment order;
// s1h/s2h = (h.a1, h.a2) PRE-SCALED by log2(e) (folded into a-vectors).
// block = (b, 8-row n-tile), 256 threads = (head 8) x (fpair 32)
// ---------------------------------------------------------------------------
__global__ __launch_bounds__(256) void k_gemm1(
    const float* __restrict__ x, const float* __restrict__ Wh,
    const float* __restrict__ ah,
    __fp16* __restrict__ hB1, float* __restrict__ s1h, float* __restrict__ s2h)
{
  int t = threadIdx.x;
  int bid = blockIdx.x;
  int b = bid / (N_ / 8);
  int n0 = (bid % (N_ / 8)) * 8;

  __shared__ float sx[8][NFEAT_];
  #pragma unroll
  for (int k = 0; k < 2; ++k) {
    int idx4 = t + k * 256;
    int r = idx4 >> 6, c4 = idx4 & 63;
    *(float4*)&sx[r][c4 * 4] =
        *(const float4*)&x[(size_t)(b * N_ + n0 + r) * NFEAT_ + c4 * 4];
  }
  __syncthreads();

  int head = t >> 5, fp = t & 31;
  float acc0[8], acc1[8];
  #pragma unroll
  for (int r = 0; r < 8; ++r) { acc0[r] = 0.f; acc1[r] = 0.f; }

  const float* wbase = Wh + (size_t)head * NFEAT_ * 64 + 2 * fp;
  for (int k = 0; k < NFEAT_; k += 4) {
    float2 w0 = *(const float2*)(wbase + (size_t)(k + 0) * 64);
    float2 w1 = *(const float2*)(wbase + (size_t)(k + 1) * 64);
    float2 w2 = *(const float2*)(wbase + (size_t)(k + 2) * 64);
    float2 w3 = *(const float2*)(wbase + (size_t)(k + 3) * 64);
    #pragma unroll
    for (int r = 0; r < 8; ++r) {
      float4 xv = *(const float4*)&sx[r][k];    // ds_read_b128
      acc0[r] = fmaf(xv.x, w0.x, acc0[r]); acc1[r] = fmaf(xv.x, w0.y, acc1[r]);
      acc0[r] = fmaf(xv.y, w1.x, acc0[r]); acc1[r] = fmaf(xv.y, w1.y, acc1[r]);
      acc0[r] = fmaf(xv.z, w2.x, acc0[r]); acc1[r] = fmaf(xv.z, w2.y, acc1[r]);
      acc0[r] = fmaf(xv.w, w3.x, acc0[r]); acc1[r] = fmaf(xv.w, w3.y, acc1[r]);
    }
  }

  // pack f16 B-fragments (elems = 8 consecutive n)
  {
    int ftile = fp >> 3;
    int lane0 = ((n0 >> 3) & 3) * 16 + ((2 * fp) & 15);
    __fp16* dst = hB1 +
        ((((size_t)(b * NHEADS_ + head) * 64 + (n0 >> 5)) * 4 + ftile) * 512 + (size_t)lane0 * 8);
    *(f16x8*)dst = pack8(acc0);
    *(f16x8*)(dst + 8) = pack8(acc1);
  }

  // fused s-dots, pre-scaled by log2(e)
  float a1_0 = ah[head * 128 + 2 * fp] * L2E;
  float a1_1 = ah[head * 128 + 2 * fp + 1] * L2E;
  float a2_0 = ah[head * 128 + 64 + 2 * fp] * L2E;
  float a2_1 = ah[head * 128 + 64 + 2 * fp + 1] * L2E;
  #pragma unroll
  for (int r = 0; r < 8; ++r) {
    float v1 = acc0[r] * a1_0 + acc1[r] * a1_1;
    float v2 = acc0[r] * a2_0 + acc1[r] * a2_1;
    #pragma unroll
    for (int off = 1; off < 32; off <<= 1) {
      v1 += __shfl_xor(v1, off, 64);
      v2 += __shfl_xor(v2, off, 64);
    }
    if (fp == 0) {
      s1h[(size_t)(b * NHEADS_ + head) * N_ + n0 + r] = v1;
      s2h[(size_t)(b * NHEADS_ + head) * N_ + n0 + r] = v2;
    }
  }
}

// ---------------------------------------------------------------------------
// GEMM2: h2 = g1@Wo (k=512,f=128); k-split across 2 thread-halves (256 thr).
// hB2 = f16 B-fragments; s1o/s2o pre-scaled by log2(e).
// ---------------------------------------------------------------------------
__global__ __launch_bounds__(256) void k_gemm2(
    const float* __restrict__ g1, const float* __restrict__ Wo,
    const float* __restrict__ ao,
    __fp16* __restrict__ hB2, float* __restrict__ s1o, float* __restrict__ s2o)
{
  int t = threadIdx.x;
  int bid = blockIdx.x;
  int b = bid / (N_ / 8);
  int n0 = (bid % (N_ / 8)) * 8;

  __shared__ float sg[8][512];
  #pragma unroll
  for (int k = 0; k < 4; ++k) {
    int idx4 = t + k * 256;                 // 1024 float4
    int r = idx4 >> 7, c4 = idx4 & 127;
    *(float4*)&sg[r][c4 * 4] =
        *(const float4*)&g1[(size_t)(b * N_ + n0 + r) * 512 + c4 * 4];
  }
  __syncthreads();

  int half = t >> 7, f = t & 127, k0 = half * 256;
  float acc[8];
  #pragma unroll
  for (int r = 0; r < 8; ++r) acc[r] = 0.f;
  const float* wp = Wo + (size_t)k0 * 128 + f;
  for (int k = 0; k < 256; k += 4) {
    float w0 = wp[(size_t)(k + 0) * 128];
    float w1 = wp[(size_t)(k + 1) * 128];
    float w2 = wp[(size_t)(k + 2) * 128];
    float w3 = wp[(size_t)(k + 3) * 128];
    #pragma unroll
    for (int r = 0; r < 8; ++r) {
      float4 g = *(const float4*)&sg[r][k0 + k];
      acc[r] = fmaf(g.x, w0, acc[r]);
      acc[r] = fmaf(g.y, w1, acc[r]);
      acc[r] = fmaf(g.z, w2, acc[r]);
      acc[r] = fmaf(g.w, w3, acc[r]);
    }
  }
  // combine k-halves through LDS (reuse sg)
  __syncthreads();
  if (half == 1) {
    #pragma unroll
    for (int r = 0; r < 8; ++r) sg[r][f] = acc[r];
  }
  __syncthreads();
  if (half == 0) {
    #pragma unroll
    for (int r = 0; r < 8; ++r) acc[r] += sg[r][f];

    int ftile = f >> 4;
    int lane0 = ((n0 >> 3) & 3) * 16 + (f & 15);
    __fp16* dst = hB2 +
        ((((size_t)b * 64 + (n0 >> 5)) * 8 + ftile) * 512 + (size_t)lane0 * 8);
    *(f16x8*)dst = pack8(acc);

    float aov1 = ao[f] * L2E;
    float aov2 = ao[128 + f] * L2E;
    __shared__ float ps1[2][8], ps2[2][8];
    int wv = f >> 6, lane = f & 63;
    #pragma unroll
    for (int r = 0; r < 8; ++r) {
      float v1 = acc[r] * aov1, v2 = acc[r] * aov2;
      #pragma unroll
      for (int off = 1; off < 64; off <<= 1) {
        v1 += __shfl_xor(v1, off, 64);
        v2 += __shfl_xor(v2, off, 64);
      }
      if (lane == 0) { ps1[wv][r] = v1; ps2[wv][r] = v2; }
    }
    __syncthreads();
    if (f < 8)       s1o[(size_t)b * N_ + n0 + f] = ps1[0][f] + ps1[1][f];
    else if (f < 16) { int r = f - 8; s2o[(size_t)b * N_ + n0 + r] = ps2[0][r] + ps2[1][r]; }
  }
}

// ---------------------------------------------------------------------------
// MFMA flash attention with PRECOMPUTED exact row-max (no online rescale).
// s1,s2 are log2e-prescaled. Per e: t0=p+s2[j]; t1=fma(.1,t0,-.9m);
// tm=max; masked select; v_exp (2^x). L deferred to one end-reduction.
// EPI0 (JCH=1): elu -> g1 f32. EPI1 (JCH=2): raw partial acc -> pO, L -> pL.
// ---------------------------------------------------------------------------
template<int EPI, int JCH>
__global__ __launch_bounds__(256) void k_att_mfma(
    const __fp16* __restrict__ hB, const float* __restrict__ s1,
    const float* __restrict__ s2, const float* __restrict__ s2max,
    const unsigned char* __restrict__ adjb,
    const float* __restrict__ bias, float* __restrict__ outp,
    float* __restrict__ pL)
{
  constexpr int H    = (EPI == 0) ? 8 : 1;
  constexpr int NFT  = (EPI == 0) ? 4 : 8;
  constexpr int KSTR = NFT * 512;
  constexpr int OSTR = (EPI == 0) ? 512 : 128;
  constexpr int JLEN = N_ / JCH;

  const int tid = threadIdx.x;
  const int l = tid & 63, wv = tid >> 6;
  const int quad = l >> 4, c15 = l & 15;

  int idx = blockIdx.x;
  const int ig = idx & 31; idx >>= 5;
  int head = 0, fs = 0, jc = 0;
  if constexpr (EPI == 0) { head = idx & 7; idx >>= 3; }
  else { fs = idx & 1; idx >>= 1; jc = idx & (JCH - 1); idx /= JCH; }
  const int b = idx;

  const int i0w = ig * 64 + wv * 16;
  const int colbase = (EPI == 0) ? head * 64 : fs * 64;

  const float* s1p = s1 + (size_t)(b * H + head) * N_;
  const float* s2p = s2 + (size_t)(b * H + head) * N_;
  const __fp16* hBp = hB + (size_t)(b * H + head) * (N_ / 32) * KSTR + fs * 2048;
  const unsigned char* abp = adjb + ((size_t)(b * N_) + i0w + c15) * (N_ / 8);

  const float s1v = s1p[i0w + c15];
  const float zm = s1v + s2max[b * H + head];
  const float m = fmaxf(zm, SLOPE_ * zm);       // exact unmasked row max
  const float p = s1v - m;
  const float cq = (SLOPE_ - 1.f) * m;          // t1 = SLOPE*t0 + cq

  float lsum = 0.f;
  f32x4 acc[4];
  #pragma unroll
  for (int t = 0; t < 4; ++t) acc[t] = (f32x4){0.f, 0.f, 0.f, 0.f};

  for (int j0 = jc * JLEN; j0 < (jc + 1) * JLEN; j0 += 64) {
    const __fp16* hk0 = hBp + (size_t)(j0 >> 5) * KSTR + (size_t)l * 8;
    f16x8 bf0[4], bf1[4];
    #pragma unroll
    for (int t = 0; t < 4; ++t) {
      bf0[t] = *(const f16x8*)(hk0 + t * 512);
      bf1[t] = *(const f16x8*)(hk0 + KSTR + t * 512);
    }
    const unsigned int mb0 = abp[(j0 >> 3) + quad];
    const unsigned int mb1 = abp[(j0 >> 3) + 4 + quad];
    float s2r[16];
    *(float4*)&s2r[0]  = *(const float4*)(s2p + j0 + quad * 8);
    *(float4*)&s2r[4]  = *(const float4*)(s2p + j0 + quad * 8 + 4);
    *(float4*)&s2r[8]  = *(const float4*)(s2p + j0 + 32 + quad * 8);
    *(float4*)&s2r[12] = *(const float4*)(s2p + j0 + 32 + quad * 8 + 4);

    float w[16];
    #pragma unroll
    for (int k = 0; k < 8; ++k) {
      float t0 = p + s2r[k];
      float t1 = fmaf(SLOPE_, t0, cq);
      float tm = fmaxf(t0, t1);
      tm = ((mb0 >> k) & 1u) ? tm : -10000.f;
      float e = __builtin_amdgcn_exp2f(tm);     // tm <= 0 always
      w[k] = e; lsum += e;
    }
    #pragma unroll
    for (int k = 0; k < 8; ++k) {
      float t0 = p + s2r[8 + k];
      float t1 = fmaf(SLOPE_, t0, cq);
      float tm = fmaxf(t0, t1);
      tm = ((mb1 >> k) & 1u) ? tm : -10000.f;
      float e = __builtin_amdgcn_exp2f(tm);
      w[8 + k] = e; lsum += e;
    }

    f16x8 a0 = pack8(w), a1 = pack8(w + 8);
    #pragma unroll
    for (int t = 0; t < 4; ++t) {
      acc[t] = __builtin_amdgcn_mfma_f32_16x16x32_f16(a0, bf0[t], acc[t], 0, 0, 0);
      acc[t] = __builtin_amdgcn_mfma_f32_16x16x32_f16(a1, bf1[t], acc[t], 0, 0, 0);
    }
  }

  lsum += __shfl_xor(lsum, 16);
  lsum += __shfl_xor(lsum, 32);

  if constexpr (EPI == 0) {
    float lr[4];
    lr[0] = 1.f / __shfl(lsum, quad * 4 + 0);
    lr[1] = 1.f / __shfl(lsum, quad * 4 + 1);
    lr[2] = 1.f / __shfl(lsum, quad * 4 + 2);
    lr[3] = 1.f / __shfl(lsum, quad * 4 + 3);
    #pragma unroll
    for (int t = 0; t < 4; ++t) {
      const float bv = bias[colbase + t * 16 + c15];
      #pragma unroll
      for (int r = 0; r < 4; ++r) {
        const int i = i0w + quad * 4 + r;
        float v = acc[t][r] * lr[r] + bv;
        v = (v > 0.f) ? v : expm1f(v);          // elu
        outp[(size_t)(b * N_ + i) * OSTR + colbase + t * 16 + c15] = v;
      }
    }
  } else {
    float* po = outp + (size_t)jc * ((size_t)B_ * N_ * 128);
    #pragma unroll
    for (int t = 0; t < 4; ++t) {
      #pragma unroll
      for (int r = 0; r < 4; ++r) {
        const int i = i0w + quad * 4 + r;
        po[(size_t)(b * N_ + i) * OSTR + colbase + t * 16 + c15] = acc[t][r];
      }
    }
    if (fs == 0 && l < 16)
      pL[(size_t)jc * (B_ * N_) + (size_t)b * N_ + i0w + l] = lsum;
  }
}

// ---------------------------------------------------------------------------
// combine att2 j-chunks: out = relu((pO0+pO1)/(pL0+pL1) + bo[f])
// ---------------------------------------------------------------------------
__global__ __launch_bounds__(256) void k_combine(
    const float* __restrict__ pO, const float* __restrict__ pL,
    const float* __restrict__ bo, float* __restrict__ out)
{
  size_t gid = (size_t)blockIdx.x * 256 + threadIdx.x;
  int f = (int)(gid & 127);
  size_t row = gid >> 7;
  float o = pO[gid] + pO[(size_t)B_ * N_ * 128 + gid];
  float L = pL[row] + pL[(size_t)B_ * N_ + row];
  float v = o / L + bo[f];
  out[gid] = fmaxf(v, 0.f);
}

// ---------------------------------------------------------------------------
extern "C" void kernel_launch(void* const* d_in, const int* in_sizes, int n_in,
                              void* d_out, int out_size, void* d_ws, size_t ws_size,
                              hipStream_t stream) {
  const float* x   = (const float*)d_in[0];
  const int*   adj = (const int*)d_in[1];
  const float* Wh  = (const float*)d_in[2];
  const float* ah  = (const float*)d_in[3];
  const float* bh  = (const float*)d_in[4];
  const float* Wo  = (const float*)d_in[5];
  const float* ao  = (const float*)d_in[6];
  const float* bo  = (const float*)d_in[7];
  float* out = (float*)d_out;

  float* ws   = (float*)d_ws;
  float* g1   = ws;                                   // B*N*512 f32
  float* s1h  = g1   + (size_t)B_ * N_ * 512;
  float* s2h  = s1h  + (size_t)B_ * NHEADS_ * N_;
  float* s1o  = s2h  + (size_t)B_ * NHEADS_ * N_;
  float* s2o  = s1o  + (size_t)B_ * N_;
  float* s2mh = s2o  + (size_t)B_ * N_;               // 32 (pad 64)
  float* s2mo = s2mh + 64;                            // 4 (pad 64)
  float* pLb  = s2mo + 64;                            // 2*B*N
  __fp16* hB1 = (__fp16*)(pLb + (size_t)2 * B_ * N_);           // 8 MB
  __fp16* hB2 = hB1 + (size_t)B_ * NHEADS_ * N_ * 64;           // 2 MB
  unsigned int* abit = (unsigned int*)(hB2 + (size_t)B_ * N_ * 128);
  float* pO = g1;    // alias: g1 fully consumed by k_gemm2 before att2 writes

  k_packadj<<<(B_ * N_ * N_ / 32) / 256, 256, 0, stream>>>(adj, abit);
  k_gemm1<<<B_ * N_ / 8, 256, 0, stream>>>(x, Wh, ah, hB1, s1h, s2h);
  k_rowmax<<<B_ * NHEADS_, 256, 0, stream>>>(s2h, s2mh);
  k_att_mfma<0, 1><<<B_ * NHEADS_ * 32, 256, 0, stream>>>(
      hB1, s1h, s2h, s2mh, (const unsigned char*)abit, bh, g1, nullptr);
  k_gemm2<<<B_ * N_ / 8, 256, 0, stream>>>(g1, Wo, ao, hB2, s1o, s2o);
  k_rowmax<<<B_, 256, 0, stream>>>(s2o, s2mo);
  k_att_mfma<1, 2><<<B_ * 2 * 32 * 2, 256, 0, stream>>>(
      hB2, s1o, s2o, s2mo, (const unsigned char*)abit, bo, pO, pLb);
  k_combine<<<(B_ * N_ * 128) / 256, 256, 0, stream>>>(pO, pLb, bo, out);
}

// Round 6
// 276.061 us; speedup vs baseline: 2.0822x; 1.0427x over previous
//
#include <hip/hip_runtime.h>

constexpr int B_ = 4;
constexpr int N_ = 2048;
constexpr int NFEAT_ = 256;
constexpr int NHEADS_ = 8;
constexpr float SLOPE_ = 0.1f;
constexpr float L2E = 1.4426950408889634f;   // log2(e)

typedef __attribute__((ext_vector_type(8))) __fp16 f16x8;
typedef __attribute__((ext_vector_type(2))) __fp16 f16x2;
typedef __attribute__((ext_vector_type(4))) float f32x4;

__device__ __forceinline__ f16x8 pack8(const float* v) {
  union { f16x2 h2[4]; f16x8 h8; } u;
  u.h2[0] = __builtin_amdgcn_cvt_pkrtz(v[0], v[1]);
  u.h2[1] = __builtin_amdgcn_cvt_pkrtz(v[2], v[3]);
  u.h2[2] = __builtin_amdgcn_cvt_pkrtz(v[4], v[5]);
  u.h2[3] = __builtin_amdgcn_cvt_pkrtz(v[6], v[7]);
  return u.h8;
}

// ---------------------------------------------------------------------------
// adj -> fragment-ordered mask: mask2[b][i16grp(128)][jt(32)][lane(64)] ushort
// lane (quad,c15): low byte = bits j=jt*64+quad*8..+8 of row i16grp*16+c15,
//                  high byte = same +32. Ballot packs 64 ints -> u64/row.
// One wave per output tile-row-group: 16 coalesced 256B loads.
// ---------------------------------------------------------------------------
__global__ __launch_bounds__(256) void k_packmask(
    const int* __restrict__ adj, unsigned short* __restrict__ mask2)
{
  const int l = threadIdx.x & 63;
  const size_t gw = ((size_t)blockIdx.x * 256 + threadIdx.x) >> 6;
  const int jt = (int)(gw & 31);
  const int ig16 = (int)((gw >> 5) & 127);
  const int b = (int)(gw >> 12);
  const int q = l >> 4, c15 = l & 15;

  const int* base = adj + ((size_t)b * N_ + ig16 * 16) * N_ + jt * 64 + l;
  unsigned int msk = 0;
  #pragma unroll
  for (int r = 0; r < 16; ++r) {
    int a = base[(size_t)r * N_];
    unsigned long long bal = __ballot(a > 0);
    unsigned int v = (unsigned int)((bal >> (q * 8)) & 0xffull)
                   | ((unsigned int)((bal >> (q * 8 + 32)) & 0xffull) << 8);
    if (r == c15) msk = v;
  }
  mask2[gw * 64 + l] = (unsigned short)msk;
}

// ---------------------------------------------------------------------------
// row max over N_ (for s2max): exact unmasked attention row-max precompute.
// ---------------------------------------------------------------------------
__global__ __launch_bounds__(256) void k_rowmax(
    const float* __restrict__ src, float* __restrict__ dst)
{
  int row = blockIdx.x, t = threadIdx.x;
  const float* p = src + (size_t)row * N_;
  float m = -INFINITY;
  #pragma unroll
  for (int k = 0; k < N_ / 256; ++k) m = fmaxf(m, p[t + k * 256]);
  #pragma unroll
  for (int off = 1; off < 64; off <<= 1) m = fmaxf(m, __shfl_xor(m, off, 64));
  __shared__ float sm[4];
  if ((t & 63) == 0) sm[t >> 6] = m;
  __syncthreads();
  if (t == 0) dst[row] = fmaxf(fmaxf(sm[0], sm[1]), fmaxf(sm[2], sm[3]));
}

// ---------------------------------------------------------------------------
// GEMM1: h = x@Wh per head; hB1 = f16 MFMA-B-fragment order;
// s1h/s2h = (h.a1, h.a2) PRE-SCALED by log2(e).
// ---------------------------------------------------------------------------
__global__ __launch_bounds__(256) void k_gemm1(
    const float* __restrict__ x, const float* __restrict__ Wh,
    const float* __restrict__ ah,
    __fp16* __restrict__ hB1, float* __restrict__ s1h, float* __restrict__ s2h)
{
  int t = threadIdx.x;
  int bid = blockIdx.x;
  int b = bid / (N_ / 8);
  int n0 = (bid % (N_ / 8)) * 8;

  __shared__ float sx[8][NFEAT_];
  #pragma unroll
  for (int k = 0; k < 2; ++k) {
    int idx4 = t + k * 256;
    int r = idx4 >> 6, c4 = idx4 & 63;
    *(float4*)&sx[r][c4 * 4] =
        *(const float4*)&x[(size_t)(b * N_ + n0 + r) * NFEAT_ + c4 * 4];
  }
  __syncthreads();

  int head = t >> 5, fp = t & 31;
  float acc0[8], acc1[8];
  #pragma unroll
  for (int r = 0; r < 8; ++r) { acc0[r] = 0.f; acc1[r] = 0.f; }

  const float* wbase = Wh + (size_t)head * NFEAT_ * 64 + 2 * fp;
  for (int k = 0; k < NFEAT_; k += 4) {
    float2 w0 = *(const float2*)(wbase + (size_t)(k + 0) * 64);
    float2 w1 = *(const float2*)(wbase + (size_t)(k + 1) * 64);
    float2 w2 = *(const float2*)(wbase + (size_t)(k + 2) * 64);
    float2 w3 = *(const float2*)(wbase + (size_t)(k + 3) * 64);
    #pragma unroll
    for (int r = 0; r < 8; ++r) {
      float4 xv = *(const float4*)&sx[r][k];
      acc0[r] = fmaf(xv.x, w0.x, acc0[r]); acc1[r] = fmaf(xv.x, w0.y, acc1[r]);
      acc0[r] = fmaf(xv.y, w1.x, acc0[r]); acc1[r] = fmaf(xv.y, w1.y, acc1[r]);
      acc0[r] = fmaf(xv.z, w2.x, acc0[r]); acc1[r] = fmaf(xv.z, w2.y, acc1[r]);
      acc0[r] = fmaf(xv.w, w3.x, acc0[r]); acc1[r] = fmaf(xv.w, w3.y, acc1[r]);
    }
  }

  {
    int ftile = fp >> 3;
    int lane0 = ((n0 >> 3) & 3) * 16 + ((2 * fp) & 15);
    __fp16* dst = hB1 +
        ((((size_t)(b * NHEADS_ + head) * 64 + (n0 >> 5)) * 4 + ftile) * 512 + (size_t)lane0 * 8);
    *(f16x8*)dst = pack8(acc0);
    *(f16x8*)(dst + 8) = pack8(acc1);
  }

  float a1_0 = ah[head * 128 + 2 * fp] * L2E;
  float a1_1 = ah[head * 128 + 2 * fp + 1] * L2E;
  float a2_0 = ah[head * 128 + 64 + 2 * fp] * L2E;
  float a2_1 = ah[head * 128 + 64 + 2 * fp + 1] * L2E;
  #pragma unroll
  for (int r = 0; r < 8; ++r) {
    float v1 = acc0[r] * a1_0 + acc1[r] * a1_1;
    float v2 = acc0[r] * a2_0 + acc1[r] * a2_1;
    #pragma unroll
    for (int off = 1; off < 32; off <<= 1) {
      v1 += __shfl_xor(v1, off, 64);
      v2 += __shfl_xor(v2, off, 64);
    }
    if (fp == 0) {
      s1h[(size_t)(b * NHEADS_ + head) * N_ + n0 + r] = v1;
      s2h[(size_t)(b * NHEADS_ + head) * N_ + n0 + r] = v2;
    }
  }
}

// ---------------------------------------------------------------------------
// GEMM2: h2 = g1@Wo (k=512,f=128); k-split x2; hB2 f16 B-fragments;
// s1o/s2o pre-scaled by log2(e).
// ---------------------------------------------------------------------------
__global__ __launch_bounds__(256) void k_gemm2(
    const float* __restrict__ g1, const float* __restrict__ Wo,
    const float* __restrict__ ao,
    __fp16* __restrict__ hB2, float* __restrict__ s1o, float* __restrict__ s2o)
{
  int t = threadIdx.x;
  int bid = blockIdx.x;
  int b = bid / (N_ / 8);
  int n0 = (bid % (N_ / 8)) * 8;

  __shared__ float sg[8][512];
  #pragma unroll
  for (int k = 0; k < 4; ++k) {
    int idx4 = t + k * 256;
    int r = idx4 >> 7, c4 = idx4 & 127;
    *(float4*)&sg[r][c4 * 4] =
        *(const float4*)&g1[(size_t)(b * N_ + n0 + r) * 512 + c4 * 4];
  }
  __syncthreads();

  int half = t >> 7, f = t & 127, k0 = half * 256;
  float acc[8];
  #pragma unroll
  for (int r = 0; r < 8; ++r) acc[r] = 0.f;
  const float* wp = Wo + (size_t)k0 * 128 + f;
  for (int k = 0; k < 256; k += 4) {
    float w0 = wp[(size_t)(k + 0) * 128];
    float w1 = wp[(size_t)(k + 1) * 128];
    float w2 = wp[(size_t)(k + 2) * 128];
    float w3 = wp[(size_t)(k + 3) * 128];
    #pragma unroll
    for (int r = 0; r < 8; ++r) {
      float4 g = *(const float4*)&sg[r][k0 + k];
      acc[r] = fmaf(g.x, w0, acc[r]);
      acc[r] = fmaf(g.y, w1, acc[r]);
      acc[r] = fmaf(g.z, w2, acc[r]);
      acc[r] = fmaf(g.w, w3, acc[r]);
    }
  }
  __syncthreads();
  if (half == 1) {
    #pragma unroll
    for (int r = 0; r < 8; ++r) sg[r][f] = acc[r];
  }
  __syncthreads();
  if (half == 0) {
    #pragma unroll
    for (int r = 0; r < 8; ++r) acc[r] += sg[r][f];

    int ftile = f >> 4;
    int lane0 = ((n0 >> 3) & 3) * 16 + (f & 15);
    __fp16* dst = hB2 +
        ((((size_t)b * 64 + (n0 >> 5)) * 8 + ftile) * 512 + (size_t)lane0 * 8);
    *(f16x8*)dst = pack8(acc);

    float aov1 = ao[f] * L2E;
    float aov2 = ao[128 + f] * L2E;
    __shared__ float ps1[2][8], ps2[2][8];
    int wv = f >> 6, lane = f & 63;
    #pragma unroll
    for (int r = 0; r < 8; ++r) {
      float v1 = acc[r] * aov1, v2 = acc[r] * aov2;
      #pragma unroll
      for (int off = 1; off < 64; off <<= 1) {
        v1 += __shfl_xor(v1, off, 64);
        v2 += __shfl_xor(v2, off, 64);
      }
      if (lane == 0) { ps1[wv][r] = v1; ps2[wv][r] = v2; }
    }
    __syncthreads();
    if (f < 8)       s1o[(size_t)b * N_ + n0 + f] = ps1[0][f] + ps1[1][f];
    else if (f < 16) { int r = f - 8; s2o[(size_t)b * N_ + n0 + r] = ps2[0][r] + ps2[1][r]; }
  }
}

// ---------------------------------------------------------------------------
// MFMA flash attention, precomputed exact row-max, 512-thread blocks:
// 8 waves = NRG row-groups x NJQ j-chunks; partials combined via LDS once.
// Mask: 1 coalesced ushort load per tile (fragment-ordered mask2).
// L row-sums via MFMA with ones-B (no per-score adds, no epilogue shuffles).
// EPI0: layer1 (H=8, 4x2), elu -> g1. EPI1: layer2 (fs col-half, 2x4),
// relu -> out directly.
// ---------------------------------------------------------------------------
template<int EPI>
__global__ __launch_bounds__(512) void k_att(
    const __fp16* __restrict__ hB, const float* __restrict__ s1,
    const float* __restrict__ s2, const float* __restrict__ s2max,
    const unsigned short* __restrict__ mask2,
    const float* __restrict__ bias, float* __restrict__ outp)
{
  constexpr int H    = (EPI == 0) ? 8 : 1;
  constexpr int NFT  = (EPI == 0) ? 4 : 8;
  constexpr int KSTR = NFT * 512;
  constexpr int OSTR = (EPI == 0) ? 512 : 128;
  constexpr int NRG  = (EPI == 0) ? 4 : 2;     // row-groups of 16 per block
  constexpr int NJQ  = 8 / NRG;                // j-chunks
  constexpr int JLEN = N_ / NJQ;
  constexpr int IBLK = NRG * 16;

  const int tid = threadIdx.x;
  const int w = tid >> 6, l = tid & 63;
  const int quad = l >> 4, c15 = l & 15;
  const int rowg = w % NRG, jq = w / NRG;

  int idx = blockIdx.x;
  const int ig = idx % (N_ / IBLK); idx /= (N_ / IBLK);
  int head = 0, fs = 0;
  if constexpr (EPI == 0) { head = idx % 8; idx /= 8; }
  else                    { fs = idx % 2; idx /= 2; }
  const int b = idx;

  const int i0w = ig * IBLK + rowg * 16;
  const int colbase = (EPI == 0) ? head * 64 : fs * 64;

  const float* s1p = s1 + (size_t)(b * H + head) * N_;
  const float* s2p = s2 + (size_t)(b * H + head) * N_;
  const __fp16* hBp = hB + (size_t)(b * H + head) * (N_ / 32) * KSTR + fs * 2048;
  const unsigned short* mp = mask2 + ((size_t)(b * 128 + (i0w >> 4)) * 32) * 64 + l;

  const float s1v = s1p[i0w + c15];
  const float zm = s1v + s2max[b * H + head];
  const float m = fmaxf(zm, SLOPE_ * zm);       // exact unmasked row max
  const float p = s1v - m;
  const float cq = (SLOPE_ - 1.f) * m;          // t1 = SLOPE*t0 + cq

  f16x8 ones;
  #pragma unroll
  for (int i = 0; i < 8; ++i) ones[i] = (__fp16)1.0f;

  f32x4 acc[4], acc5;
  #pragma unroll
  for (int t = 0; t < 4; ++t) acc[t] = (f32x4){0.f, 0.f, 0.f, 0.f};
  acc5 = (f32x4){0.f, 0.f, 0.f, 0.f};

  for (int j0 = jq * JLEN; j0 < (jq + 1) * JLEN; j0 += 64) {
    const __fp16* hk0 = hBp + (size_t)(j0 >> 5) * KSTR + (size_t)l * 8;
    f16x8 bf0[4], bf1[4];
    #pragma unroll
    for (int t = 0; t < 4; ++t) {
      bf0[t] = *(const f16x8*)(hk0 + t * 512);
      bf1[t] = *(const f16x8*)(hk0 + KSTR + t * 512);
    }
    const unsigned int msk = mp[(size_t)(j0 >> 6) * 64];   // coalesced 128B/wave
    float s2r[16];
    *(float4*)&s2r[0]  = *(const float4*)(s2p + j0 + quad * 8);
    *(float4*)&s2r[4]  = *(const float4*)(s2p + j0 + quad * 8 + 4);
    *(float4*)&s2r[8]  = *(const float4*)(s2p + j0 + 32 + quad * 8);
    *(float4*)&s2r[12] = *(const float4*)(s2p + j0 + 32 + quad * 8 + 4);

    float wgt[16];
    #pragma unroll
    for (int k = 0; k < 16; ++k) {
      float t0 = p + s2r[k];
      float t1 = fmaf(SLOPE_, t0, cq);
      float tm = fmaxf(t0, t1);
      tm = ((msk >> k) & 1u) ? tm : -10000.f;
      wgt[k] = __builtin_amdgcn_exp2f(tm);      // tm <= 0 always
    }

    f16x8 a0 = pack8(wgt), a1 = pack8(wgt + 8);
    acc5 = __builtin_amdgcn_mfma_f32_16x16x32_f16(a0, ones, acc5, 0, 0, 0);
    acc5 = __builtin_amdgcn_mfma_f32_16x16x32_f16(a1, ones, acc5, 0, 0, 0);
    #pragma unroll
    for (int t = 0; t < 4; ++t) {
      acc[t] = __builtin_amdgcn_mfma_f32_16x16x32_f16(a0, bf0[t], acc[t], 0, 0, 0);
      acc[t] = __builtin_amdgcn_mfma_f32_16x16x32_f16(a1, bf1[t], acc[t], 0, 0, 0);
    }
  }

  // ---- combine partials across j-chunks through LDS (one barrier) ----
  __shared__ float pacc[NJQ - 1][NRG][16][64];
  __shared__ float pls[NJQ - 1][NRG][16];
  if (jq > 0) {
    #pragma unroll
    for (int t = 0; t < 4; ++t)
      #pragma unroll
      for (int r = 0; r < 4; ++r)
        pacc[jq - 1][rowg][quad * 4 + r][t * 16 + c15] = acc[t][r];
    if (c15 == 0) {
      #pragma unroll
      for (int r = 0; r < 4; ++r)
        pls[jq - 1][rowg][quad * 4 + r] = acc5[r];
    }
  }
  __syncthreads();
  if (jq == 0) {
    float Lrow[4];
    #pragma unroll
    for (int r = 0; r < 4; ++r) Lrow[r] = acc5[r];
    #pragma unroll
    for (int q = 0; q < NJQ - 1; ++q) {
      #pragma unroll
      for (int t = 0; t < 4; ++t)
        #pragma unroll
        for (int r = 0; r < 4; ++r)
          acc[t][r] += pacc[q][rowg][quad * 4 + r][t * 16 + c15];
      #pragma unroll
      for (int r = 0; r < 4; ++r) Lrow[r] += pls[q][rowg][quad * 4 + r];
    }
    float lr[4];
    #pragma unroll
    for (int r = 0; r < 4; ++r) lr[r] = 1.f / Lrow[r];

    #pragma unroll
    for (int t = 0; t < 4; ++t) {
      const float bv = bias[colbase + t * 16 + c15];
      #pragma unroll
      for (int r = 0; r < 4; ++r) {
        const int i = i0w + quad * 4 + r;
        float v = acc[t][r] * lr[r] + bv;
        if constexpr (EPI == 0) v = (v > 0.f) ? v : expm1f(v);  // elu
        else                    v = fmaxf(v, 0.f);              // relu(elu)=relu
        outp[(size_t)(b * N_ + i) * OSTR + colbase + t * 16 + c15] = v;
      }
    }
  }
}

// ---------------------------------------------------------------------------
extern "C" void kernel_launch(void* const* d_in, const int* in_sizes, int n_in,
                              void* d_out, int out_size, void* d_ws, size_t ws_size,
                              hipStream_t stream) {
  const float* x   = (const float*)d_in[0];
  const int*   adj = (const int*)d_in[1];
  const float* Wh  = (const float*)d_in[2];
  const float* ah  = (const float*)d_in[3];
  const float* bh  = (const float*)d_in[4];
  const float* Wo  = (const float*)d_in[5];
  const float* ao  = (const float*)d_in[6];
  const float* bo  = (const float*)d_in[7];
  float* out = (float*)d_out;

  float* ws   = (float*)d_ws;
  float* g1   = ws;                                   // B*N*512 f32
  float* s1h  = g1   + (size_t)B_ * N_ * 512;
  float* s2h  = s1h  + (size_t)B_ * NHEADS_ * N_;
  float* s1o  = s2h  + (size_t)B_ * NHEADS_ * N_;
  float* s2o  = s1o  + (size_t)B_ * N_;
  float* s2mh = s2o  + (size_t)B_ * N_;               // 32 (pad 64)
  float* s2mo = s2mh + 64;                            // 4 (pad 64)
  __fp16* hB1 = (__fp16*)(s2mo + 64);                           // 8 MB
  __fp16* hB2 = hB1 + (size_t)B_ * NHEADS_ * N_ * 64;           // 2 MB
  unsigned short* mask2 = (unsigned short*)(hB2 + (size_t)B_ * N_ * 128); // 2 MB

  k_packmask<<<(B_ * 128 * 32 * 64) / 256, 256, 0, stream>>>(adj, mask2);
  k_gemm1<<<B_ * N_ / 8, 256, 0, stream>>>(x, Wh, ah, hB1, s1h, s2h);
  k_rowmax<<<B_ * NHEADS_, 256, 0, stream>>>(s2h, s2mh);
  k_att<0><<<B_ * NHEADS_ * (N_ / 64), 512, 0, stream>>>(
      hB1, s1h, s2h, s2mh, mask2, bh, g1);
  k_gemm2<<<B_ * N_ / 8, 256, 0, stream>>>(g1, Wo, ao, hB2, s1o, s2o);
  k_rowmax<<<B_, 256, 0, stream>>>(s2o, s2mo);
  k_att<1><<<B_ * 2 * (N_ / 32), 512, 0, stream>>>(
      hB2, s1o, s2o, s2mo, mask2, bo, out);
}

// Round 7
// 270.324 us; speedup vs baseline: 2.1264x; 1.0212x over previous
//
#include <hip/hip_runtime.h>

constexpr int B_ = 4;
constexpr int N_ = 2048;
constexpr int NFEAT_ = 256;
constexpr int NHEADS_ = 8;
constexpr float SLOPE_ = 0.1f;
constexpr float L2E = 1.4426950408889634f;   // log2(e)

typedef __attribute__((ext_vector_type(8))) __fp16 f16x8;
typedef __attribute__((ext_vector_type(2))) __fp16 f16x2;
typedef __attribute__((ext_vector_type(4))) float f32x4;

__device__ __forceinline__ f16x8 pack8(const float* v) {
  union { f16x2 h2[4]; f16x8 h8; } u;
  u.h2[0] = __builtin_amdgcn_cvt_pkrtz(v[0], v[1]);
  u.h2[1] = __builtin_amdgcn_cvt_pkrtz(v[2], v[3]);
  u.h2[2] = __builtin_amdgcn_cvt_pkrtz(v[4], v[5]);
  u.h2[3] = __builtin_amdgcn_cvt_pkrtz(v[6], v[7]);
  return u.h8;
}

// ---------------------------------------------------------------------------
// adj -> fragment-ordered mask: mask2[b][i16grp(128)][jt(32)][lane(64)] ushort
// ---------------------------------------------------------------------------
__global__ __launch_bounds__(256) void k_packmask(
    const int* __restrict__ adj, unsigned short* __restrict__ mask2)
{
  const int l = threadIdx.x & 63;
  const size_t gw = ((size_t)blockIdx.x * 256 + threadIdx.x) >> 6;
  const int jt = (int)(gw & 31);
  const int ig16 = (int)((gw >> 5) & 127);
  const int b = (int)(gw >> 12);
  const int q = l >> 4, c15 = l & 15;

  const int* base = adj + ((size_t)b * N_ + ig16 * 16) * N_ + jt * 64 + l;
  unsigned int msk = 0;
  #pragma unroll
  for (int r = 0; r < 16; ++r) {
    int a = base[(size_t)r * N_];
    unsigned long long bal = __ballot(a > 0);
    unsigned int v = (unsigned int)((bal >> (q * 8)) & 0xffull)
                   | ((unsigned int)((bal >> (q * 8 + 32)) & 0xffull) << 8);
    if (r == c15) msk = v;
  }
  mask2[gw * 64 + l] = (unsigned short)msk;
}

// ---------------------------------------------------------------------------
// row max over N_ (for s2max): exact unmasked attention row-max precompute.
// ---------------------------------------------------------------------------
__global__ __launch_bounds__(256) void k_rowmax(
    const float* __restrict__ src, float* __restrict__ dst)
{
  int row = blockIdx.x, t = threadIdx.x;
  const float* p = src + (size_t)row * N_;
  float m = -INFINITY;
  #pragma unroll
  for (int k = 0; k < N_ / 256; ++k) m = fmaxf(m, p[t + k * 256]);
  #pragma unroll
  for (int off = 1; off < 64; off <<= 1) m = fmaxf(m, __shfl_xor(m, off, 64));
  __shared__ float sm[4];
  if ((t & 63) == 0) sm[t >> 6] = m;
  __syncthreads();
  if (t == 0) dst[row] = fmaxf(fmaxf(sm[0], sm[1]), fmaxf(sm[2], sm[3]));
}

// ---------------------------------------------------------------------------
// GEMM1: h = x@Wh per head; hB1 = f16 MFMA-B-fragment order;
// s1h/s2h = (h.a1, h.a2) PRE-SCALED by log2(e).
// ---------------------------------------------------------------------------
__global__ __launch_bounds__(256, 4) void k_gemm1(
    const float* __restrict__ x, const float* __restrict__ Wh,
    const float* __restrict__ ah,
    __fp16* __restrict__ hB1, float* __restrict__ s1h, float* __restrict__ s2h)
{
  int t = threadIdx.x;
  int bid = blockIdx.x;
  int b = bid / (N_ / 8);
  int n0 = (bid % (N_ / 8)) * 8;

  __shared__ float sx[8][NFEAT_];
  #pragma unroll
  for (int k = 0; k < 2; ++k) {
    int idx4 = t + k * 256;
    int r = idx4 >> 6, c4 = idx4 & 63;
    *(float4*)&sx[r][c4 * 4] =
        *(const float4*)&x[(size_t)(b * N_ + n0 + r) * NFEAT_ + c4 * 4];
  }
  __syncthreads();

  int head = t >> 5, fp = t & 31;
  float acc0[8], acc1[8];
  #pragma unroll
  for (int r = 0; r < 8; ++r) { acc0[r] = 0.f; acc1[r] = 0.f; }

  const float* wbase = Wh + (size_t)head * NFEAT_ * 64 + 2 * fp;
  for (int k = 0; k < NFEAT_; k += 4) {
    float2 w0 = *(const float2*)(wbase + (size_t)(k + 0) * 64);
    float2 w1 = *(const float2*)(wbase + (size_t)(k + 1) * 64);
    float2 w2 = *(const float2*)(wbase + (size_t)(k + 2) * 64);
    float2 w3 = *(const float2*)(wbase + (size_t)(k + 3) * 64);
    #pragma unroll
    for (int r = 0; r < 8; ++r) {
      float4 xv = *(const float4*)&sx[r][k];
      acc0[r] = fmaf(xv.x, w0.x, acc0[r]); acc1[r] = fmaf(xv.x, w0.y, acc1[r]);
      acc0[r] = fmaf(xv.y, w1.x, acc0[r]); acc1[r] = fmaf(xv.y, w1.y, acc1[r]);
      acc0[r] = fmaf(xv.z, w2.x, acc0[r]); acc1[r] = fmaf(xv.z, w2.y, acc1[r]);
      acc0[r] = fmaf(xv.w, w3.x, acc0[r]); acc1[r] = fmaf(xv.w, w3.y, acc1[r]);
    }
  }

  {
    int ftile = fp >> 3;
    int lane0 = ((n0 >> 3) & 3) * 16 + ((2 * fp) & 15);
    __fp16* dst = hB1 +
        ((((size_t)(b * NHEADS_ + head) * 64 + (n0 >> 5)) * 4 + ftile) * 512 + (size_t)lane0 * 8);
    *(f16x8*)dst = pack8(acc0);
    *(f16x8*)(dst + 8) = pack8(acc1);
  }

  float a1_0 = ah[head * 128 + 2 * fp] * L2E;
  float a1_1 = ah[head * 128 + 2 * fp + 1] * L2E;
  float a2_0 = ah[head * 128 + 64 + 2 * fp] * L2E;
  float a2_1 = ah[head * 128 + 64 + 2 * fp + 1] * L2E;
  #pragma unroll
  for (int r = 0; r < 8; ++r) {
    float v1 = acc0[r] * a1_0 + acc1[r] * a1_1;
    float v2 = acc0[r] * a2_0 + acc1[r] * a2_1;
    #pragma unroll
    for (int off = 1; off < 32; off <<= 1) {
      v1 += __shfl_xor(v1, off, 64);
      v2 += __shfl_xor(v2, off, 64);
    }
    if (fp == 0) {
      s1h[(size_t)(b * NHEADS_ + head) * N_ + n0 + r] = v1;
      s2h[(size_t)(b * NHEADS_ + head) * N_ + n0 + r] = v2;
    }
  }
}

// ---------------------------------------------------------------------------
// GEMM2: h2 = g1@Wo (k=512,f=128); k-split x2; hB2 f16 B-fragments;
// s1o/s2o pre-scaled by log2(e).
// ---------------------------------------------------------------------------
__global__ __launch_bounds__(256, 4) void k_gemm2(
    const float* __restrict__ g1, const float* __restrict__ Wo,
    const float* __restrict__ ao,
    __fp16* __restrict__ hB2, float* __restrict__ s1o, float* __restrict__ s2o)
{
  int t = threadIdx.x;
  int bid = blockIdx.x;
  int b = bid / (N_ / 8);
  int n0 = (bid % (N_ / 8)) * 8;

  __shared__ float sg[8][512];
  #pragma unroll
  for (int k = 0; k < 4; ++k) {
    int idx4 = t + k * 256;
    int r = idx4 >> 7, c4 = idx4 & 127;
    *(float4*)&sg[r][c4 * 4] =
        *(const float4*)&g1[(size_t)(b * N_ + n0 + r) * 512 + c4 * 4];
  }
  __syncthreads();

  int half = t >> 7, f = t & 127, k0 = half * 256;
  float acc[8];
  #pragma unroll
  for (int r = 0; r < 8; ++r) acc[r] = 0.f;
  const float* wp = Wo + (size_t)k0 * 128 + f;
  for (int k = 0; k < 256; k += 4) {
    float w0 = wp[(size_t)(k + 0) * 128];
    float w1 = wp[(size_t)(k + 1) * 128];
    float w2 = wp[(size_t)(k + 2) * 128];
    float w3 = wp[(size_t)(k + 3) * 128];
    #pragma unroll
    for (int r = 0; r < 8; ++r) {
      float4 g = *(const float4*)&sg[r][k0 + k];
      acc[r] = fmaf(g.x, w0, acc[r]);
      acc[r] = fmaf(g.y, w1, acc[r]);
      acc[r] = fmaf(g.z, w2, acc[r]);
      acc[r] = fmaf(g.w, w3, acc[r]);
    }
  }
  __syncthreads();
  if (half == 1) {
    #pragma unroll
    for (int r = 0; r < 8; ++r) sg[r][f] = acc[r];
  }
  __syncthreads();
  if (half == 0) {
    #pragma unroll
    for (int r = 0; r < 8; ++r) acc[r] += sg[r][f];

    int ftile = f >> 4;
    int lane0 = ((n0 >> 3) & 3) * 16 + (f & 15);
    __fp16* dst = hB2 +
        ((((size_t)b * 64 + (n0 >> 5)) * 8 + ftile) * 512 + (size_t)lane0 * 8);
    *(f16x8*)dst = pack8(acc);

    float aov1 = ao[f] * L2E;
    float aov2 = ao[128 + f] * L2E;
    __shared__ float ps1[2][8], ps2[2][8];
    int wv = f >> 6, lane = f & 63;
    #pragma unroll
    for (int r = 0; r < 8; ++r) {
      float v1 = acc[r] * aov1, v2 = acc[r] * aov2;
      #pragma unroll
      for (int off = 1; off < 64; off <<= 1) {
        v1 += __shfl_xor(v1, off, 64);
        v2 += __shfl_xor(v2, off, 64);
      }
      if (lane == 0) { ps1[wv][r] = v1; ps2[wv][r] = v2; }
    }
    __syncthreads();
    if (f < 8)       s1o[(size_t)b * N_ + n0 + f] = ps1[0][f] + ps1[1][f];
    else if (f < 16) { int r = f - 8; s2o[(size_t)b * N_ + n0 + r] = ps2[0][r] + ps2[1][r]; }
  }
}

// ---------------------------------------------------------------------------
// MFMA flash attention, precomputed exact row-max, 512-thread blocks:
// 8 waves = NRG row-groups x NJQ j-chunks; partials combined via LDS once.
// __launch_bounds__(512, 4): 128-VGPR cap so the whole tile working set
// (8 V-frags + s2r + wgt + acc) stays register-resident and loads batch.
// ---------------------------------------------------------------------------
template<int EPI>
__global__ __launch_bounds__(512, 4) void k_att(
    const __fp16* __restrict__ hB, const float* __restrict__ s1,
    const float* __restrict__ s2, const float* __restrict__ s2max,
    const unsigned short* __restrict__ mask2,
    const float* __restrict__ bias, float* __restrict__ outp)
{
  constexpr int H    = (EPI == 0) ? 8 : 1;
  constexpr int NFT  = (EPI == 0) ? 4 : 8;
  constexpr int KSTR = NFT * 512;
  constexpr int OSTR = (EPI == 0) ? 512 : 128;
  constexpr int NRG  = (EPI == 0) ? 4 : 2;     // row-groups of 16 per block
  constexpr int NJQ  = 8 / NRG;                // j-chunks
  constexpr int JLEN = N_ / NJQ;
  constexpr int IBLK = NRG * 16;

  const int tid = threadIdx.x;
  const int w = tid >> 6, l = tid & 63;
  const int quad = l >> 4, c15 = l & 15;
  const int rowg = w % NRG, jq = w / NRG;

  int idx = blockIdx.x;
  const int ig = idx % (N_ / IBLK); idx /= (N_ / IBLK);
  int head = 0, fs = 0;
  if constexpr (EPI == 0) { head = idx % 8; idx /= 8; }
  else                    { fs = idx % 2; idx /= 2; }
  const int b = idx;

  const int i0w = ig * IBLK + rowg * 16;
  const int colbase = (EPI == 0) ? head * 64 : fs * 64;

  const float* s1p = s1 + (size_t)(b * H + head) * N_;
  const float* s2p = s2 + (size_t)(b * H + head) * N_;
  const __fp16* hBp = hB + (size_t)(b * H + head) * (N_ / 32) * KSTR + fs * 2048;
  const unsigned short* mp = mask2 + ((size_t)(b * 128 + (i0w >> 4)) * 32) * 64 + l;

  const float s1v = s1p[i0w + c15];
  const float zm = s1v + s2max[b * H + head];
  const float m = fmaxf(zm, SLOPE_ * zm);       // exact unmasked row max
  const float p = s1v - m;
  const float cq = (SLOPE_ - 1.f) * m;          // t1 = SLOPE*t0 + cq

  f16x8 ones;
  #pragma unroll
  for (int i = 0; i < 8; ++i) ones[i] = (__fp16)1.0f;

  f32x4 acc[4], acc5;
  #pragma unroll
  for (int t = 0; t < 4; ++t) acc[t] = (f32x4){0.f, 0.f, 0.f, 0.f};
  acc5 = (f32x4){0.f, 0.f, 0.f, 0.f};

  for (int j0 = jq * JLEN; j0 < (jq + 1) * JLEN; j0 += 64) {
    const __fp16* hk0 = hBp + (size_t)(j0 >> 5) * KSTR + (size_t)l * 8;
    f16x8 bf0[4], bf1[4];
    #pragma unroll
    for (int t = 0; t < 4; ++t) {
      bf0[t] = *(const f16x8*)(hk0 + t * 512);
      bf1[t] = *(const f16x8*)(hk0 + KSTR + t * 512);
    }
    const unsigned int msk = mp[(size_t)(j0 >> 6) * 64];   // coalesced 128B/wave
    float s2r[16];
    *(float4*)&s2r[0]  = *(const float4*)(s2p + j0 + quad * 8);
    *(float4*)&s2r[4]  = *(const float4*)(s2p + j0 + quad * 8 + 4);
    *(float4*)&s2r[8]  = *(const float4*)(s2p + j0 + 32 + quad * 8);
    *(float4*)&s2r[12] = *(const float4*)(s2p + j0 + 32 + quad * 8 + 4);

    float wgt[16];
    #pragma unroll
    for (int k = 0; k < 16; ++k) {
      float t0 = p + s2r[k];
      float t1 = fmaf(SLOPE_, t0, cq);
      float tm = fmaxf(t0, t1);                 // tm <= 0 always
      float e = __builtin_amdgcn_exp2f(tm);
      int sel = (int)(msk << (31 - k)) >> 31;   // all-ones iff bit k set
      union { float f; int i; } u; u.f = e; u.i &= sel;
      wgt[k] = u.f;
    }

    f16x8 a0 = pack8(wgt), a1 = pack8(wgt + 8);
    acc5 = __builtin_amdgcn_mfma_f32_16x16x32_f16(a0, ones, acc5, 0, 0, 0);
    acc5 = __builtin_amdgcn_mfma_f32_16x16x32_f16(a1, ones, acc5, 0, 0, 0);
    #pragma unroll
    for (int t = 0; t < 4; ++t) {
      acc[t] = __builtin_amdgcn_mfma_f32_16x16x32_f16(a0, bf0[t], acc[t], 0, 0, 0);
      acc[t] = __builtin_amdgcn_mfma_f32_16x16x32_f16(a1, bf1[t], acc[t], 0, 0, 0);
    }
  }

  // ---- combine partials across j-chunks through LDS (one barrier) ----
  __shared__ float pacc[NJQ - 1][NRG][16][64];
  __shared__ float pls[NJQ - 1][NRG][16];
  if (jq > 0) {
    #pragma unroll
    for (int t = 0; t < 4; ++t)
      #pragma unroll
      for (int r = 0; r < 4; ++r)
        pacc[jq - 1][rowg][quad * 4 + r][t * 16 + c15] = acc[t][r];
    if (c15 == 0) {
      #pragma unroll
      for (int r = 0; r < 4; ++r)
        pls[jq - 1][rowg][quad * 4 + r] = acc5[r];
    }
  }
  __syncthreads();
  if (jq == 0) {
    float Lrow[4];
    #pragma unroll
    for (int r = 0; r < 4; ++r) Lrow[r] = acc5[r];
    #pragma unroll
    for (int q = 0; q < NJQ - 1; ++q) {
      #pragma unroll
      for (int t = 0; t < 4; ++t)
        #pragma unroll
        for (int r = 0; r < 4; ++r)
          acc[t][r] += pacc[q][rowg][quad * 4 + r][t * 16 + c15];
      #pragma unroll
      for (int r = 0; r < 4; ++r) Lrow[r] += pls[q][rowg][quad * 4 + r];
    }
    float lr[4];
    #pragma unroll
    for (int r = 0; r < 4; ++r) lr[r] = 1.f / Lrow[r];

    #pragma unroll
    for (int t = 0; t < 4; ++t) {
      const float bv = bias[colbase + t * 16 + c15];
      #pragma unroll
      for (int r = 0; r < 4; ++r) {
        const int i = i0w + quad * 4 + r;
        float v = acc[t][r] * lr[r] + bv;
        if constexpr (EPI == 0) v = (v > 0.f) ? v : expm1f(v);  // elu
        else                    v = fmaxf(v, 0.f);              // relu(elu)=relu
        outp[(size_t)(b * N_ + i) * OSTR + colbase + t * 16 + c15] = v;
      }
    }
  }
}

// ---------------------------------------------------------------------------
extern "C" void kernel_launch(void* const* d_in, const int* in_sizes, int n_in,
                              void* d_out, int out_size, void* d_ws, size_t ws_size,
                              hipStream_t stream) {
  const float* x   = (const float*)d_in[0];
  const int*   adj = (const int*)d_in[1];
  const float* Wh  = (const float*)d_in[2];
  const float* ah  = (const float*)d_in[3];
  const float* bh  = (const float*)d_in[4];
  const float* Wo  = (const float*)d_in[5];
  const float* ao  = (const float*)d_in[6];
  const float* bo  = (const float*)d_in[7];
  float* out = (float*)d_out;

  float* ws   = (float*)d_ws;
  float* g1   = ws;                                   // B*N*512 f32
  float* s1h  = g1   + (size_t)B_ * N_ * 512;
  float* s2h  = s1h  + (size_t)B_ * NHEADS_ * N_;
  float* s1o  = s2h  + (size_t)B_ * NHEADS_ * N_;
  float* s2o  = s1o  + (size_t)B_ * N_;
  float* s2mh = s2o  + (size_t)B_ * N_;               // 32 (pad 64)
  float* s2mo = s2mh + 64;                            // 4 (pad 64)
  __fp16* hB1 = (__fp16*)(s2mo + 64);                           // 8 MB
  __fp16* hB2 = hB1 + (size_t)B_ * NHEADS_ * N_ * 64;           // 2 MB
  unsigned short* mask2 = (unsigned short*)(hB2 + (size_t)B_ * N_ * 128); // 2 MB

  k_packmask<<<(B_ * 128 * 32 * 64) / 256, 256, 0, stream>>>(adj, mask2);
  k_gemm1<<<B_ * N_ / 8, 256, 0, stream>>>(x, Wh, ah, hB1, s1h, s2h);
  k_rowmax<<<B_ * NHEADS_, 256, 0, stream>>>(s2h, s2mh);
  k_att<0><<<B_ * NHEADS_ * (N_ / 64), 512, 0, stream>>>(
      hB1, s1h, s2h, s2mh, mask2, bh, g1);
  k_gemm2<<<B_ * N_ / 8, 256, 0, stream>>>(g1, Wo, ao, hB2, s1o, s2o);
  k_rowmax<<<B_, 256, 0, stream>>>(s2o, s2mo);
  k_att<1><<<B_ * 2 * (N_ / 32), 512, 0, stream>>>(
      hB2, s1o, s2o, s2mo, mask2, bo, out);
}

// Round 8
// 225.426 us; speedup vs baseline: 2.5499x; 1.1992x over previous
//
#include <hip/hip_runtime.h>

constexpr int B_ = 4;
constexpr int N_ = 2048;
constexpr int NFEAT_ = 256;
constexpr int NHEADS_ = 8;
constexpr float SLOPE_ = 0.1f;
constexpr float L2E = 1.4426950408889634f;   // log2(e)

typedef __attribute__((ext_vector_type(8))) __fp16 f16x8;
typedef __attribute__((ext_vector_type(2))) __fp16 f16x2;
typedef __attribute__((ext_vector_type(4))) float f32x4;

__device__ __forceinline__ f16x8 pack8(const float* v) {
  union { f16x2 h2[4]; f16x8 h8; } u;
  u.h2[0] = __builtin_amdgcn_cvt_pkrtz(v[0], v[1]);
  u.h2[1] = __builtin_amdgcn_cvt_pkrtz(v[2], v[3]);
  u.h2[2] = __builtin_amdgcn_cvt_pkrtz(v[4], v[5]);
  u.h2[3] = __builtin_amdgcn_cvt_pkrtz(v[6], v[7]);
  return u.h8;
}

// ---------------------------------------------------------------------------
// adj -> fragment-ordered mask: mask2[b][i16grp(128)][jt(32)][lane(64)] ushort
// ---------------------------------------------------------------------------
__global__ __launch_bounds__(256) void k_packmask(
    const int* __restrict__ adj, unsigned short* __restrict__ mask2)
{
  const int l = threadIdx.x & 63;
  const size_t gw = ((size_t)blockIdx.x * 256 + threadIdx.x) >> 6;
  const int jt = (int)(gw & 31);
  const int ig16 = (int)((gw >> 5) & 127);
  const int b = (int)(gw >> 12);
  const int q = l >> 4, c15 = l & 15;

  const int* base = adj + ((size_t)b * N_ + ig16 * 16) * N_ + jt * 64 + l;
  unsigned int msk = 0;
  #pragma unroll
  for (int r = 0; r < 16; ++r) {
    int a = base[(size_t)r * N_];
    unsigned long long bal = __ballot(a > 0);
    unsigned int v = (unsigned int)((bal >> (q * 8)) & 0xffull)
                   | ((unsigned int)((bal >> (q * 8 + 32)) & 0xffull) << 8);
    if (r == c15) msk = v;
  }
  mask2[gw * 64 + l] = (unsigned short)msk;
}

// ---------------------------------------------------------------------------
// row max over N_ (for s2max)
// ---------------------------------------------------------------------------
__global__ __launch_bounds__(256) void k_rowmax(
    const float* __restrict__ src, float* __restrict__ dst)
{
  int row = blockIdx.x, t = threadIdx.x;
  const float* p = src + (size_t)row * N_;
  float m = -INFINITY;
  #pragma unroll
  for (int k = 0; k < N_ / 256; ++k) m = fmaxf(m, p[t + k * 256]);
  #pragma unroll
  for (int off = 1; off < 64; off <<= 1) m = fmaxf(m, __shfl_xor(m, off, 64));
  __shared__ float sm[4];
  if ((t & 63) == 0) sm[t >> 6] = m;
  __syncthreads();
  if (t == 0) dst[row] = fmaxf(fmaxf(sm[0], sm[1]), fmaxf(sm[2], sm[3]));
}

// ---------------------------------------------------------------------------
// Wh f32 [8][256][64] -> WhB f16 MFMA-B-frag [h][ks 8][ft 4][lane 64][8]
//   B[k=quad*8+j][col=c15]
// ---------------------------------------------------------------------------
__global__ __launch_bounds__(256) void k_prepwh(
    const float* __restrict__ Wh, __fp16* __restrict__ WhB)
{
  int l = threadIdx.x & 63;
  int s = (int)((blockIdx.x * 256 + threadIdx.x) >> 6);   // 0..255
  int h = s >> 5, ks = (s >> 2) & 7, ft = s & 3;
  const float* src = Wh + ((size_t)h * 256 + ks * 32 + (l >> 4) * 8) * 64 + ft * 16 + (l & 15);
  float v[8];
  #pragma unroll
  for (int j = 0; j < 8; ++j) v[j] = src[(size_t)j * 64];
  *(f16x8*)(WhB + (size_t)s * 512 + l * 8) = pack8(v);
}

// ---------------------------------------------------------------------------
// Wo f32 [512][128] -> WoB f16 B-frag [ks 16][ft 8][lane 64][8]
// ---------------------------------------------------------------------------
__global__ __launch_bounds__(256) void k_prepwo(
    const float* __restrict__ Wo, __fp16* __restrict__ WoB)
{
  int l = threadIdx.x & 63;
  int s = (int)((blockIdx.x * 256 + threadIdx.x) >> 6);   // 0..127
  int ks = s >> 3, ft = s & 7;
  const float* src = Wo + ((size_t)ks * 32 + (l >> 4) * 8) * 128 + ft * 16 + (l & 15);
  float v[8];
  #pragma unroll
  for (int j = 0; j < 8; ++j) v[j] = src[(size_t)j * 128];
  *(f16x8*)(WoB + (size_t)s * 512 + l * 8) = pack8(v);
}

// ---------------------------------------------------------------------------
// GEMM1 (MFMA): block = 16 n-rows x ALL 512 f (8 heads), 256 thr = 4 waves.
// Wave w covers heads 2w,2w+1 (8 ftiles), K=256 in 8 ksteps.
// x staged once (f16, padded) -> 1 ds_read_b128 A-frag per kstep.
// Outputs: hB1 f16 B-frag (via LDS transpose), s1h/s2h (L2E-prescaled).
// ---------------------------------------------------------------------------
__global__ __launch_bounds__(256, 4) void k_gemm1(
    const float* __restrict__ x, const __fp16* __restrict__ WhB,
    const float* __restrict__ ah,
    __fp16* __restrict__ hB1, float* __restrict__ s1h, float* __restrict__ s2h)
{
  constexpr int XP = 264;                      // padded row stride (f16)
  __shared__ __fp16 xs[16 * XP];               // 8.25 KB
  __shared__ __fp16 hT[512 * 16];              // 16 KB, [f][n]

  const int t = threadIdx.x;
  const int bid = blockIdx.x;
  const int b = bid >> 7;
  const int n0 = (bid & 127) * 16;

  {  // stage x -> f16
    int r = t >> 4, k0 = (t & 15) * 16;
    const float* src = x + ((size_t)(b * N_) + n0 + r) * NFEAT_ + k0;
    float v0[8], v1[8];
    *(float4*)&v0[0] = *(const float4*)(src);
    *(float4*)&v0[4] = *(const float4*)(src + 4);
    *(float4*)&v1[0] = *(const float4*)(src + 8);
    *(float4*)&v1[4] = *(const float4*)(src + 12);
    *(f16x8*)&xs[r * XP + k0] = pack8(v0);
    *(f16x8*)&xs[r * XP + k0 + 8] = pack8(v1);
  }
  __syncthreads();

  const int w = t >> 6, l = t & 63;
  const int quad = l >> 4, c15 = l & 15;

  f32x4 acc[8];
  #pragma unroll
  for (int i = 0; i < 8; ++i) acc[i] = (f32x4){0.f, 0.f, 0.f, 0.f};

  for (int ks = 0; ks < 8; ++ks) {
    f16x8 af = *(const f16x8*)&xs[c15 * XP + ks * 32 + quad * 8];
    #pragma unroll
    for (int tt = 0; tt < 8; ++tt) {
      int hl = tt >> 2, ft = tt & 3;
      f16x8 bf = *(const f16x8*)(WhB +
          ((((size_t)(2 * w + hl) * 8 + ks) * 4 + ft) * 512) + l * 8);
      acc[tt] = __builtin_amdgcn_mfma_f32_16x16x32_f16(af, bf, acc[tt], 0, 0, 0);
    }
  }

  // fused s-dots (per head fully inside this wave), pre-scaled by log2(e)
  #pragma unroll
  for (int hl = 0; hl < 2; ++hl) {
    int head = 2 * w + hl;
    float a1v[4], a2v[4];
    #pragma unroll
    for (int ft = 0; ft < 4; ++ft) {
      a1v[ft] = ah[head * 128 + ft * 16 + c15] * L2E;
      a2v[ft] = ah[head * 128 + 64 + ft * 16 + c15] * L2E;
    }
    #pragma unroll
    for (int r = 0; r < 4; ++r) {
      float v1 = 0.f, v2 = 0.f;
      #pragma unroll
      for (int ft = 0; ft < 4; ++ft) {
        v1 = fmaf(acc[hl * 4 + ft][r], a1v[ft], v1);
        v2 = fmaf(acc[hl * 4 + ft][r], a2v[ft], v2);
      }
      #pragma unroll
      for (int off = 1; off < 16; off <<= 1) {
        v1 += __shfl_xor(v1, off, 64);
        v2 += __shfl_xor(v2, off, 64);
      }
      if (c15 == 0) {
        s1h[(size_t)(b * NHEADS_ + head) * N_ + n0 + quad * 4 + r] = v1;
        s2h[(size_t)(b * NHEADS_ + head) * N_ + n0 + quad * 4 + r] = v2;
      }
    }
  }

  // transpose into hT[f][n]
  #pragma unroll
  for (int tt = 0; tt < 8; ++tt) {
    int f = (2 * w + (tt >> 2)) * 64 + (tt & 3) * 16 + c15;
    #pragma unroll
    for (int r = 0; r < 4; ++r)
      hT[f * 16 + quad * 4 + r] = (__fp16)acc[tt][r];
  }
  __syncthreads();

  // coalesced B-frag stores: 1024 slots of 8 n-elems, 4 per thread
  const int base_oct = (n0 >> 3) & 3;
  #pragma unroll
  for (int q = 0; q < 4; ++q) {
    int s = t + q * 256;
    int c15v = s & 15, oct = (s >> 4) & 1, ft = (s >> 5) & 3, head = s >> 7;
    f16x8 v = *(const f16x8*)&hT[(head * 64 + ft * 16 + c15v) * 16 + oct * 8];
    int lane0 = (base_oct + oct) * 16 + c15v;
    *(f16x8*)(hB1 +
        ((((size_t)(b * NHEADS_ + head) * 64 + (n0 >> 5)) * 4 + ft) * 512) + lane0 * 8) = v;
  }
}

// ---------------------------------------------------------------------------
// GEMM2 (MFMA): block = 16 n-rows x 128 f, 256 thr = 4 waves (2 ftiles each),
// K=512 in 16 ksteps. g1 is f16 (written by att1). Outputs hB2 B-frag +
// s1o/s2o (L2E-prescaled, cross-wave combine via LDS).
// ---------------------------------------------------------------------------
__global__ __launch_bounds__(256, 4) void k_gemm2(
    const __fp16* __restrict__ g1, const __fp16* __restrict__ WoB,
    const float* __restrict__ ao,
    __fp16* __restrict__ hB2, float* __restrict__ s1o, float* __restrict__ s2o)
{
  constexpr int GP = 520;                      // padded row stride (f16)
  __shared__ __fp16 gs[16 * GP];               // 16.25 KB
  __shared__ __fp16 hT[128 * 16];              // 4 KB
  __shared__ float sd1[4][16], sd2[4][16];

  const int t = threadIdx.x;
  const int bid = blockIdx.x;
  const int b = bid >> 7;
  const int n0 = (bid & 127) * 16;

  {  // stage g1 (already f16)
    int r = t >> 4, k0 = (t & 15) * 32;
    const __fp16* src = g1 + ((size_t)(b * N_) + n0 + r) * 512 + k0;
    #pragma unroll
    for (int i = 0; i < 4; ++i)
      *(f16x8*)&gs[r * GP + k0 + i * 8] = *(const f16x8*)(src + i * 8);
  }
  __syncthreads();

  const int w = t >> 6, l = t & 63;
  const int quad = l >> 4, c15 = l & 15;

  f32x4 acc[2];
  acc[0] = (f32x4){0.f, 0.f, 0.f, 0.f};
  acc[1] = (f32x4){0.f, 0.f, 0.f, 0.f};

  for (int ks = 0; ks < 16; ++ks) {
    f16x8 af = *(const f16x8*)&gs[c15 * GP + ks * 32 + quad * 8];
    #pragma unroll
    for (int tt = 0; tt < 2; ++tt) {
      int ft = 2 * w + tt;
      f16x8 bf = *(const f16x8*)(WoB + (((size_t)ks * 8 + ft) * 512) + l * 8);
      acc[tt] = __builtin_amdgcn_mfma_f32_16x16x32_f16(af, bf, acc[tt], 0, 0, 0);
    }
  }

  // s-dot partials over this wave's 32 f
  {
    float a1v[2], a2v[2];
    #pragma unroll
    for (int tt = 0; tt < 2; ++tt) {
      int f = (2 * w + tt) * 16 + c15;
      a1v[tt] = ao[f] * L2E;
      a2v[tt] = ao[128 + f] * L2E;
    }
    #pragma unroll
    for (int r = 0; r < 4; ++r) {
      float v1 = acc[0][r] * a1v[0] + acc[1][r] * a1v[1];
      float v2 = acc[0][r] * a2v[0] + acc[1][r] * a2v[1];
      #pragma unroll
      for (int off = 1; off < 16; off <<= 1) {
        v1 += __shfl_xor(v1, off, 64);
        v2 += __shfl_xor(v2, off, 64);
      }
      if (c15 == 0) { sd1[w][quad * 4 + r] = v1; sd2[w][quad * 4 + r] = v2; }
    }
  }

  // transpose into hT[f][n]
  #pragma unroll
  for (int tt = 0; tt < 2; ++tt) {
    int f = (2 * w + tt) * 16 + c15;
    #pragma unroll
    for (int r = 0; r < 4; ++r)
      hT[f * 16 + quad * 4 + r] = (__fp16)acc[tt][r];
  }
  __syncthreads();

  if (t < 16)
    s1o[(size_t)b * N_ + n0 + t] = sd1[0][t] + sd1[1][t] + sd1[2][t] + sd1[3][t];
  else if (t < 32) {
    int rr = t - 16;
    s2o[(size_t)b * N_ + n0 + rr] = sd2[0][rr] + sd2[1][rr] + sd2[2][rr] + sd2[3][rr];
  }

  // coalesced B-frag stores: 256 slots, 1 per thread
  {
    int c15v = t & 15, oct = (t >> 4) & 1, ft = t >> 5;
    f16x8 v = *(const f16x8*)&hT[(ft * 16 + c15v) * 16 + oct * 8];
    int base_oct = (n0 >> 3) & 3;
    int lane0 = (base_oct + oct) * 16 + c15v;
    *(f16x8*)(hB2 +
        (((size_t)(b * 64 + (n0 >> 5)) * 8 + ft) * 512) + lane0 * 8) = v;
  }
}

// ---------------------------------------------------------------------------
// MFMA flash attention (unchanged from R7 except EPI0 writes f16 g1).
// ---------------------------------------------------------------------------
template<int EPI>
__global__ __launch_bounds__(512, 4) void k_att(
    const __fp16* __restrict__ hB, const float* __restrict__ s1,
    const float* __restrict__ s2, const float* __restrict__ s2max,
    const unsigned short* __restrict__ mask2,
    const float* __restrict__ bias, void* __restrict__ outp)
{
  constexpr int H    = (EPI == 0) ? 8 : 1;
  constexpr int NFT  = (EPI == 0) ? 4 : 8;
  constexpr int KSTR = NFT * 512;
  constexpr int OSTR = (EPI == 0) ? 512 : 128;
  constexpr int NRG  = (EPI == 0) ? 4 : 2;
  constexpr int NJQ  = 8 / NRG;
  constexpr int JLEN = N_ / NJQ;
  constexpr int IBLK = NRG * 16;

  const int tid = threadIdx.x;
  const int w = tid >> 6, l = tid & 63;
  const int quad = l >> 4, c15 = l & 15;
  const int rowg = w % NRG, jq = w / NRG;

  int idx = blockIdx.x;
  const int ig = idx % (N_ / IBLK); idx /= (N_ / IBLK);
  int head = 0, fs = 0;
  if constexpr (EPI == 0) { head = idx % 8; idx /= 8; }
  else                    { fs = idx % 2; idx /= 2; }
  const int b = idx;

  const int i0w = ig * IBLK + rowg * 16;
  const int colbase = (EPI == 0) ? head * 64 : fs * 64;

  const float* s1p = s1 + (size_t)(b * H + head) * N_;
  const float* s2p = s2 + (size_t)(b * H + head) * N_;
  const __fp16* hBp = hB + (size_t)(b * H + head) * (N_ / 32) * KSTR + fs * 2048;
  const unsigned short* mp = mask2 + ((size_t)(b * 128 + (i0w >> 4)) * 32) * 64 + l;

  const float s1v = s1p[i0w + c15];
  const float zm = s1v + s2max[b * H + head];
  const float m = fmaxf(zm, SLOPE_ * zm);
  const float p = s1v - m;
  const float cq = (SLOPE_ - 1.f) * m;

  f16x8 ones;
  #pragma unroll
  for (int i = 0; i < 8; ++i) ones[i] = (__fp16)1.0f;

  f32x4 acc[4], acc5;
  #pragma unroll
  for (int t = 0; t < 4; ++t) acc[t] = (f32x4){0.f, 0.f, 0.f, 0.f};
  acc5 = (f32x4){0.f, 0.f, 0.f, 0.f};

  for (int j0 = jq * JLEN; j0 < (jq + 1) * JLEN; j0 += 64) {
    const __fp16* hk0 = hBp + (size_t)(j0 >> 5) * KSTR + (size_t)l * 8;
    f16x8 bf0[4], bf1[4];
    #pragma unroll
    for (int t = 0; t < 4; ++t) {
      bf0[t] = *(const f16x8*)(hk0 + t * 512);
      bf1[t] = *(const f16x8*)(hk0 + KSTR + t * 512);
    }
    const unsigned int msk = mp[(size_t)(j0 >> 6) * 64];
    float s2r[16];
    *(float4*)&s2r[0]  = *(const float4*)(s2p + j0 + quad * 8);
    *(float4*)&s2r[4]  = *(const float4*)(s2p + j0 + quad * 8 + 4);
    *(float4*)&s2r[8]  = *(const float4*)(s2p + j0 + 32 + quad * 8);
    *(float4*)&s2r[12] = *(const float4*)(s2p + j0 + 32 + quad * 8 + 4);

    float wgt[16];
    #pragma unroll
    for (int k = 0; k < 16; ++k) {
      float t0 = p + s2r[k];
      float t1 = fmaf(SLOPE_, t0, cq);
      float tm = fmaxf(t0, t1);
      float e = __builtin_amdgcn_exp2f(tm);
      int sel = (int)(msk << (31 - k)) >> 31;
      union { float f; int i; } u; u.f = e; u.i &= sel;
      wgt[k] = u.f;
    }

    f16x8 a0 = pack8(wgt), a1 = pack8(wgt + 8);
    acc5 = __builtin_amdgcn_mfma_f32_16x16x32_f16(a0, ones, acc5, 0, 0, 0);
    acc5 = __builtin_amdgcn_mfma_f32_16x16x32_f16(a1, ones, acc5, 0, 0, 0);
    #pragma unroll
    for (int t = 0; t < 4; ++t) {
      acc[t] = __builtin_amdgcn_mfma_f32_16x16x32_f16(a0, bf0[t], acc[t], 0, 0, 0);
      acc[t] = __builtin_amdgcn_mfma_f32_16x16x32_f16(a1, bf1[t], acc[t], 0, 0, 0);
    }
  }

  __shared__ float pacc[NJQ - 1][NRG][16][64];
  __shared__ float pls[NJQ - 1][NRG][16];
  if (jq > 0) {
    #pragma unroll
    for (int t = 0; t < 4; ++t)
      #pragma unroll
      for (int r = 0; r < 4; ++r)
        pacc[jq - 1][rowg][quad * 4 + r][t * 16 + c15] = acc[t][r];
    if (c15 == 0) {
      #pragma unroll
      for (int r = 0; r < 4; ++r)
        pls[jq - 1][rowg][quad * 4 + r] = acc5[r];
    }
  }
  __syncthreads();
  if (jq == 0) {
    float Lrow[4];
    #pragma unroll
    for (int r = 0; r < 4; ++r) Lrow[r] = acc5[r];
    #pragma unroll
    for (int q = 0; q < NJQ - 1; ++q) {
      #pragma unroll
      for (int t = 0; t < 4; ++t)
        #pragma unroll
        for (int r = 0; r < 4; ++r)
          acc[t][r] += pacc[q][rowg][quad * 4 + r][t * 16 + c15];
      #pragma unroll
      for (int r = 0; r < 4; ++r) Lrow[r] += pls[q][rowg][quad * 4 + r];
    }
    float lr[4];
    #pragma unroll
    for (int r = 0; r < 4; ++r) lr[r] = 1.f / Lrow[r];

    #pragma unroll
    for (int t = 0; t < 4; ++t) {
      const float bv = bias[colbase + t * 16 + c15];
      #pragma unroll
      for (int r = 0; r < 4; ++r) {
        const int i = i0w + quad * 4 + r;
        float v = acc[t][r] * lr[r] + bv;
        if constexpr (EPI == 0) {
          v = (v > 0.f) ? v : expm1f(v);      // elu
          ((__fp16*)outp)[(size_t)(b * N_ + i) * OSTR + colbase + t * 16 + c15] = (__fp16)v;
        } else {
          v = fmaxf(v, 0.f);                  // relu(elu)=relu
          ((float*)outp)[(size_t)(b * N_ + i) * OSTR + colbase + t * 16 + c15] = v;
        }
      }
    }
  }
}

// ---------------------------------------------------------------------------
extern "C" void kernel_launch(void* const* d_in, const int* in_sizes, int n_in,
                              void* d_out, int out_size, void* d_ws, size_t ws_size,
                              hipStream_t stream) {
  const float* x   = (const float*)d_in[0];
  const int*   adj = (const int*)d_in[1];
  const float* Wh  = (const float*)d_in[2];
  const float* ah  = (const float*)d_in[3];
  const float* bh  = (const float*)d_in[4];
  const float* Wo  = (const float*)d_in[5];
  const float* ao  = (const float*)d_in[6];
  const float* bo  = (const float*)d_in[7];
  float* out = (float*)d_out;

  float* ws   = (float*)d_ws;
  float* s1h  = ws;                                   // B*8*N
  float* s2h  = s1h  + (size_t)B_ * NHEADS_ * N_;
  float* s1o  = s2h  + (size_t)B_ * NHEADS_ * N_;     // B*N
  float* s2o  = s1o  + (size_t)B_ * N_;
  float* s2mh = s2o  + (size_t)B_ * N_;               // 32 (pad 64)
  float* s2mo = s2mh + 64;                            // 4 (pad 64)
  __fp16* g1  = (__fp16*)(s2mo + 64);                 // B*N*512 f16 (8 MB)
  __fp16* hB1 = g1  + (size_t)B_ * N_ * 512;          // 8 MB
  __fp16* hB2 = hB1 + (size_t)B_ * NHEADS_ * N_ * 64; // 2 MB
  __fp16* WhB = hB2 + (size_t)B_ * N_ * 128;          // 256 KB
  __fp16* WoB = WhB + (size_t)8 * 256 * 64;           // 128 KB
  unsigned short* mask2 = (unsigned short*)(WoB + (size_t)512 * 128); // 2 MB

  k_packmask<<<(B_ * 128 * 32 * 64) / 256, 256, 0, stream>>>(adj, mask2);
  k_prepwh<<<64, 256, 0, stream>>>(Wh, WhB);
  k_prepwo<<<32, 256, 0, stream>>>(Wo, WoB);
  k_gemm1<<<B_ * (N_ / 16), 256, 0, stream>>>(x, WhB, ah, hB1, s1h, s2h);
  k_rowmax<<<B_ * NHEADS_, 256, 0, stream>>>(s2h, s2mh);
  k_att<0><<<B_ * NHEADS_ * (N_ / 64), 512, 0, stream>>>(
      hB1, s1h, s2h, s2mh, mask2, bh, (void*)g1);
  k_gemm2<<<B_ * (N_ / 16), 256, 0, stream>>>(g1, WoB, ao, hB2, s1o, s2o);
  k_rowmax<<<B_, 256, 0, stream>>>(s2o, s2mo);
  k_att<1><<<B_ * 2 * (N_ / 32), 512, 0, stream>>>(
      hB2, s1o, s2o, s2mo, mask2, bo, (void*)out);
}